// Round 10
// baseline (358.555 us; speedup 1.0000x reference)
//
#include <hip/hip_runtime.h>
#include <math.h>

#define NTOK 4096
#define IND 768
#define DD 256
#define DD2 512
#define DHH 128
#define NEXP 51
#define TM 32
#define NTILE_MAX 179
#define NWCONV 968
#define NBLK_MAX 512
#define SMEM_BYTES 72960

typedef __attribute__((ext_vector_type(4))) float f32x4;
typedef __attribute__((ext_vector_type(8))) short short8;

__device__ __forceinline__ float gelu_f(float x) {
    return 0.5f * x * (1.0f + erff(x * 0.70710678118654752440f));
}
__device__ __forceinline__ ushort f2bf(float x) {
    unsigned u = __float_as_uint(x);
    return (ushort)((u + 0x7fffu + ((u >> 16) & 1u)) >> 16);
}

struct KArgs {
    const float *tokens, *ln_g, *ln_b, *pw1, *pb1, *pw2, *pb2, *emb;
    const float *sw1, *sb1, *sw2, *sb2, *ew1, *eb1, *ew2, *eb2;
    const float *spw1, *spb1, *spw2, *spb2, *lw1, *lb1, *lw2, *lb2;
    const float *fw, *fb, *fg, *fbeta, *aW, *ab, *ag, *abt;
    const float *dw1, *db1, *dw2, *db2;
    const int *levels, *ph, *pw;
    ushort *x_ln, *h1, *enh;
    float *h, *e_pre;
    ushort *pw1T, *pw2T, *fwT, *aWT, *dw1T;
    float *ctail;
    int *sorted, *tpos, *tcnt, *texp, *meta, *bar;
    float *out;
    int nblk;
};

// grid barrier: monotonic counter, agent-scope release/acquire (cross-XCD safe)
__device__ __forceinline__ void gsync(int* bar, int target) {
    __syncthreads();
    if (threadIdx.x == 0) {
        __threadfence();
        __hip_atomic_fetch_add(bar, 1, __ATOMIC_RELEASE, __HIP_MEMORY_SCOPE_AGENT);
        while (__hip_atomic_load(bar, __ATOMIC_ACQUIRE, __HIP_MEMORY_SCOPE_AGENT) < target)
            __builtin_amdgcn_s_sleep(2);
    }
    __syncthreads();
}

__global__ __launch_bounds__(256, 2) void k_mega(KArgs a) {
    __shared__ __align__(16) char sm[SMEM_BYTES];
    int tid = threadIdx.x;
    int blk = blockIdx.x;
    int nblk = a.nblk;

    // ================= phase 0: grouping (blk 0) / transpose+stats (others) =================
    if (blk == 0) {
        int* cnt = (int*)sm;
        int* cur = cnt + NEXP;
        int* offS = cur + NEXP;
        int* tileoff = offS + NEXP + 1;
        int* expS = tileoff + NEXP + 1;
        float* hs = (float*)(expS + NTOK);
        float* hl = hs + 64;
        float* cf = hl + 64;
        if (tid < NEXP) cnt[tid] = 0;
        if (tid < 64) {
            float p0 = (float)a.ph[0], p1 = (float)a.pw[0];
            float lvl = (float)a.levels[0];
            hs[tid] = fmaxf(0.f, p0 * a.spw1[tid] + p1 * a.spw1[64 + tid] + a.spb1[tid]);
            hl[tid] = fmaxf(0.f, lvl * a.lw1[tid] + a.lb1[tid]);
        }
        __syncthreads();
        int myidx[16];
        #pragma unroll
        for (int i = 0; i < 16; ++i) {
            int n = tid + i * 256;
            int id = min(max(a.levels[n * 2], 0), NEXP - 1);
            myidx[i] = id;
            atomicAdd(&cnt[id], 1);
        }
        if (tid < 64) {
            float v = a.spb2[tid];
            for (int j = 0; j < 64; ++j) v += hs[j] * a.spw2[j * 64 + tid];
            cf[tid] = v;
        } else if (tid < 128) {
            int k = tid - 64;
            float v = a.lb2[k];
            for (int j = 0; j < 64; ++j) v += hl[j] * a.lw2[j * 64 + k];
            cf[64 + k] = v;
        }
        __syncthreads();
        if (tid == 0) {
            int acc = 0, ta = 0;
            for (int e = 0; e < NEXP; ++e) {
                offS[e] = acc; cur[e] = acc; tileoff[e] = ta;
                ta += (cnt[e] + TM - 1) / TM;
                acc += cnt[e];
            }
            offS[NEXP] = acc; tileoff[NEXP] = ta;
            a.meta[0] = ta;
        }
        __syncthreads();
        #pragma unroll
        for (int i = 0; i < 16; ++i) {
            int n = tid + i * 256;
            int p = atomicAdd(&cur[myidx[i]], 1);
            a.sorted[p] = n;
            expS[p] = myidx[i];
        }
        {
            float v = a.fb[tid];
            for (int j = 0; j < 128; ++j) v += cf[j] * a.fw[(size_t)(128 + j) * DD + tid];
            a.ctail[tid] = v;
        }
        __syncthreads();
        #pragma unroll
        for (int i = 0; i < 16; ++i) {
            int p = tid + i * 256;
            int e = expS[p];
            int rel = p - offS[e];
            if ((rel & (TM - 1)) == 0) {
                int ti = tileoff[e] + (rel / TM);
                a.tpos[ti] = p;
                a.tcnt[ti] = min(TM, offS[e + 1] - p);
                a.texp[ti] = e;
            }
        }
    } else {
        for (int job = blk - 1; job < NWCONV + NTOK; job += nblk - 1) {
            __syncthreads();
            if (job < NWCONV) {
                float (*T)[65] = (float(*)[65])sm;
                int b = job;
                const float* src; ushort* dst; int R, C;
                if (b < 96)       { src = a.pw1; dst = a.pw1T; R = IND; C = DD2; }
                else if (b < 128) { b -= 96;  src = a.pw2; dst = a.pw2T; R = DD2; C = DD; }
                else if (b < 144) { b -= 128; src = a.fw;  dst = a.fwT;  R = DD;  C = DD; }
                else if (b < 152) { b -= 144; src = a.dw1; dst = a.dw1T; R = DD;  C = DHH; }
                else { b -= 152; int e = b >> 4; b &= 15;
                       src = a.aW + (size_t)e * DD * DD; dst = a.aWT + (size_t)e * DD * DD;
                       R = DD; C = DD; }
                int tpc = C >> 6;
                int tr = b / tpc, tc = b - tr * tpc;
                int lr = tid >> 6, lc = tid & 63;
                #pragma unroll
                for (int i = 0; i < 16; ++i) {
                    int r = i * 4 + lr;
                    T[r][lc] = src[(size_t)(tr * 64 + r) * C + tc * 64 + lc];
                }
                __syncthreads();
                #pragma unroll
                for (int i = 0; i < 16; ++i) {
                    int r = i * 4 + lr;
                    dst[(size_t)(tc * 64 + r) * R + tr * 64 + lc] = f2bf(T[lc][r]);
                }
            } else {
                int n = job - NWCONV;
                float* red = (float*)sm;
                float* hid = (float*)(sm + 64);
                const float* x = a.tokens + (size_t)n * IND;
                float v[3];
                float s = 0.f, s2 = 0.f, es = 0.f;
                #pragma unroll
                for (int i = 0; i < 3; ++i) {
                    int e = tid + i * 256;
                    float xv = x[e];
                    v[i] = xv;
                    s += xv; s2 += xv * xv;
                    if (e > 0) es += fabsf(xv - x[e - 1]);
                }
                float vals[3] = {s, s2, es};
                #pragma unroll
                for (int q = 0; q < 3; ++q) {
                    float vv = vals[q];
                    #pragma unroll
                    for (int o = 32; o > 0; o >>= 1) vv += __shfl_down(vv, o);
                    int lane = tid & 63, w = tid >> 6;
                    if (lane == 0) red[w] = vv;
                    __syncthreads();
                    vals[q] = red[0] + red[1] + red[2] + red[3];
                    __syncthreads();
                }
                s = vals[0]; s2 = vals[1]; es = vals[2];
                float mean = s * (1.f / 768.f);
                float var_u = (s2 - 768.f * mean * mean) * (1.f / 767.f);
                float rstd = rsqrtf(s2 * (1.f / 768.f) - mean * mean + 1e-5f);
                float edge = es * (1.f / 767.f);
                #pragma unroll
                for (int i = 0; i < 3; ++i) {
                    int e = tid + i * 256;
                    a.x_ln[(size_t)n * IND + e] = f2bf((v[i] - mean) * rstd * a.ln_g[e] + a.ln_b[e]);
                }
                if (tid < 64) {
                    hid[tid] = fmaxf(0.f, var_u * a.sw1[tid] + mean * a.sw1[64 + tid] + a.sb1[tid]);
                } else if (tid < 128) {
                    int j = tid - 64;
                    hid[64 + j] = fmaxf(0.f, edge * a.ew1[j] + a.eb1[j]);
                }
                __syncthreads();
                ushort* er = a.enh + (size_t)n * DHH;
                if (tid < 64) {
                    float v2 = a.sb2[tid];
                    for (int j = 0; j < 64; ++j) v2 += hid[j] * a.sw2[j * 64 + tid];
                    er[tid] = f2bf(v2);
                } else if (tid < 128) {
                    int k = tid - 64;
                    float v2 = a.eb2[k];
                    for (int j = 0; j < 64; ++j) v2 += hid[64 + j] * a.ew2[j * 64 + k];
                    er[64 + k] = f2bf(v2);
                }
            }
        }
    }
    gsync(a.bar, nblk);

    // ================= phase A: GEMM1 h1 = gelu(x_ln @ pw1T^T + pb1) =================
    {
        ushort (*Al)[72] = (ushort(*)[72])sm;
        ushort (*Bl)[72] = (ushort(*)[72])(sm + 64 * 72 * 2);
        int w = tid >> 6, lane = tid & 63;
        int g = lane >> 4, mr = lane & 15;
        for (int t = blk; t < 512; t += nblk) {
            __syncthreads();
            int bm = (t >> 3) * 64, bn = (t & 7) * 64;
            f32x4 acc[4];
            #pragma unroll
            for (int f = 0; f < 4; ++f) acc[f] = (f32x4){0.f, 0.f, 0.f, 0.f};
            for (int k0 = 0; k0 < IND; k0 += 64) {
                #pragma unroll
                for (int i = 0; i < 2; ++i) {
                    int c = tid + 256 * i;
                    int r = c >> 3, c8 = (c & 7) * 8;
                    *(short8*)&Al[r][c8] = *(const short8*)(a.x_ln + (size_t)(bm + r) * IND + k0 + c8);
                }
                #pragma unroll
                for (int i = 0; i < 2; ++i) {
                    int c = tid + 256 * i;
                    int r = c >> 3, c8 = (c & 7) * 8;
                    *(short8*)&Bl[r][c8] = *(const short8*)(a.pw1T + (size_t)(bn + r) * IND + k0 + c8);
                }
                __syncthreads();
                #pragma unroll
                for (int kk = 0; kk < 64; kk += 32) {
                    short8 av = *(const short8*)&Al[16 * w + mr][kk + g * 8];
                    #pragma unroll
                    for (int f = 0; f < 4; ++f) {
                        short8 bv = *(const short8*)&Bl[16 * f + mr][kk + g * 8];
                        acc[f] = __builtin_amdgcn_mfma_f32_16x16x32_bf16(av, bv, acc[f], 0, 0, 0);
                    }
                }
                __syncthreads();
            }
            #pragma unroll
            for (int f = 0; f < 4; ++f) {
                int col = bn + 16 * f + mr;
                float bv = a.pb1[col];
                #pragma unroll
                for (int r = 0; r < 4; ++r) {
                    int row = bm + 16 * w + 4 * g + r;
                    a.h1[(size_t)row * DD2 + col] = f2bf(gelu_f(acc[f][r] + bv));
                }
            }
        }
    }
    gsync(a.bar, 2 * nblk);

    // ================= phase B: GEMM2 (h) + GEMM3 (e_pre) =================
    {
        ushort (*Al)[72] = (ushort(*)[72])sm;
        ushort (*Bl)[72] = (ushort(*)[72])(sm + 64 * 72 * 2);
        int w = tid >> 6, lane = tid & 63;
        int g = lane >> 4, mr = lane & 15;
        for (int t = blk; t < 512; t += nblk) {
            __syncthreads();
            int by = t >> 2, bx = t & 3;
            const ushort* A; const ushort* BT; const float* bias; float* Cf;
            int K, sA, sB, epi, bm;
            if (by < 64) { A = a.h1; BT = a.pw2T; bias = a.pb2; Cf = a.h; K = DD2; sA = DD2; sB = DD2; epi = 2; bm = by * 64; }
            else         { A = a.enh; BT = a.fwT; bias = a.ctail; Cf = a.e_pre; K = DHH; sA = DHH; sB = DD; epi = 0; bm = (by - 64) * 64; }
            int bn = bx * 64;
            f32x4 acc[4];
            #pragma unroll
            for (int f = 0; f < 4; ++f) acc[f] = (f32x4){0.f, 0.f, 0.f, 0.f};
            for (int k0 = 0; k0 < K; k0 += 64) {
                #pragma unroll
                for (int i = 0; i < 2; ++i) {
                    int c = tid + 256 * i;
                    int r = c >> 3, c8 = (c & 7) * 8;
                    *(short8*)&Al[r][c8] = *(const short8*)(A + (size_t)(bm + r) * sA + k0 + c8);
                }
                #pragma unroll
                for (int i = 0; i < 2; ++i) {
                    int c = tid + 256 * i;
                    int r = c >> 3, c8 = (c & 7) * 8;
                    *(short8*)&Bl[r][c8] = *(const short8*)(BT + (size_t)(bn + r) * sB + k0 + c8);
                }
                __syncthreads();
                #pragma unroll
                for (int kk = 0; kk < 64; kk += 32) {
                    short8 av = *(const short8*)&Al[16 * w + mr][kk + g * 8];
                    #pragma unroll
                    for (int f = 0; f < 4; ++f) {
                        short8 bv = *(const short8*)&Bl[16 * f + mr][kk + g * 8];
                        acc[f] = __builtin_amdgcn_mfma_f32_16x16x32_bf16(av, bv, acc[f], 0, 0, 0);
                    }
                }
                __syncthreads();
            }
            #pragma unroll
            for (int f = 0; f < 4; ++f) {
                int col = bn + 16 * f + mr;
                float bv = bias[col];
                #pragma unroll
                for (int r = 0; r < 4; ++r) {
                    int row = bm + 16 * w + 4 * g + r;
                    float v = acc[f][r] + bv;
                    if (epi == 2) {
                        int id = min(max(a.levels[row * 2], 0), NEXP - 1);
                        v += a.emb[(size_t)id * DD + col];
                    }
                    Cf[(size_t)row * DD + col] = v;
                }
            }
        }
    }
    gsync(a.bar, 3 * nblk);

    // ================= phase C: fused adapter =================
    {
        int ntile = a.meta[0];
        for (int bt = blk; bt < ntile; bt += nblk) {
            __syncthreads();
            ushort (*Alf)[264] = (ushort(*)[264])sm;
            char* BlRaw = sm + 16896;
            ushort (*Dl)[72] = (ushort(*)[72])(sm + 53760);
            int* tokS = (int*)(sm + 72192);
            float* gateS = (float*)(sm + 72320);
            float (*pg)[TM] = (float(*)[TM])(sm + 72448);
            int w = tid >> 6, lane = tid & 63;
            int g = lane >> 4, mr = lane & 15;
            int e = a.texp[bt], base = a.tpos[bt], nv = a.tcnt[bt];
            if (tid < TM) tokS[tid] = a.sorted[base + min(tid, nv - 1)];
            __syncthreads();
            // hfull
            #pragma unroll
            for (int i = 0; i < 8; ++i) {
                int r = w * 8 + i;
                int tok = tokS[r];
                float4 e4 = *(const float4*)(a.e_pre + (size_t)tok * DD + lane * 4);
                float s = e4.x + e4.y + e4.z + e4.w;
                float s2 = e4.x * e4.x + e4.y * e4.y + e4.z * e4.z + e4.w * e4.w;
                #pragma unroll
                for (int o = 1; o < 64; o <<= 1) { s += __shfl_xor(s, o); s2 += __shfl_xor(s2, o); }
                float m = s * (1.f / 256.f);
                float rs = rsqrtf(s2 * (1.f / 256.f) - m * m + 1e-5f);
                float4 h4 = *(const float4*)(a.h + (size_t)tok * DD + lane * 4);
                float4 g4 = *(const float4*)(a.fg + lane * 4);
                float4 b4 = *(const float4*)(a.fbeta + lane * 4);
                ushort4 o4;
                o4.x = f2bf(h4.x + 0.3f * gelu_f((e4.x - m) * rs * g4.x + b4.x));
                o4.y = f2bf(h4.y + 0.3f * gelu_f((e4.y - m) * rs * g4.y + b4.y));
                o4.z = f2bf(h4.z + 0.3f * gelu_f((e4.z - m) * rs * g4.z + b4.z));
                o4.w = f2bf(h4.w + 0.3f * gelu_f((e4.w - m) * rs * g4.w + b4.w));
                *(ushort4*)&Alf[r][lane * 4] = o4;
            }
            __syncthreads();
            // expert GEMM [32x256]
            ushort* Bl = (ushort*)BlRaw;
            const ushort* We = a.aWT + (size_t)e * DD * DD;
            int mt = w & 1, nfh = w >> 1;
            f32x4 acc[8];
            #pragma unroll
            for (int q = 0; q < 8; ++q) acc[q] = (f32x4){0.f, 0.f, 0.f, 0.f};
            for (int k0 = 0; k0 < DD; k0 += 64) {
                #pragma unroll
                for (int i = 0; i < 8; ++i) {
                    int c = tid + 256 * i;
                    int r = c >> 3, c8 = (c & 7) * 8;
                    *(short8*)&Bl[r * 72 + c8] = *(const short8*)(We + (size_t)r * DD + k0 + c8);
                }
                __syncthreads();
                #pragma unroll
                for (int kk = 0; kk < 64; kk += 32) {
                    short8 av = *(const short8*)&Alf[16 * mt + mr][k0 + kk + g * 8];
                    #pragma unroll
                    for (int q = 0; q < 8; ++q) {
                        short8 bv = *(const short8*)&Bl[(128 * nfh + 16 * q + mr) * 72 + kk + g * 8];
                        acc[q] = __builtin_amdgcn_mfma_f32_16x16x32_bf16(av, bv, acc[q], 0, 0, 0);
                    }
                }
                __syncthreads();
            }
            // yf32 = acc + ab
            float* yf32 = (float*)BlRaw;
            #pragma unroll
            for (int q = 0; q < 8; ++q) {
                int col = 128 * nfh + 16 * q + mr;
                float abv = a.ab[(size_t)e * DD + col];
                #pragma unroll
                for (int r = 0; r < 4; ++r) {
                    int row = 16 * mt + 4 * g + r;
                    yf32[row * 260 + col] = acc[q][r] + abv;
                }
            }
            __syncthreads();
            // row LN + gelu
            #pragma unroll
            for (int i = 0; i < 8; ++i) {
                int r = w * 8 + i;
                float4 v = *(const float4*)&yf32[r * 260 + lane * 4];
                float s = v.x + v.y + v.z + v.w;
                float s2 = v.x * v.x + v.y * v.y + v.z * v.z + v.w * v.w;
                #pragma unroll
                for (int o = 1; o < 64; o <<= 1) { s += __shfl_xor(s, o); s2 += __shfl_xor(s2, o); }
                float m = s * (1.f / 256.f);
                float rs = rsqrtf(s2 * (1.f / 256.f) - m * m + 1e-5f);
                float4 gg = *(const float4*)(a.ag + (size_t)e * DD + lane * 4);
                float4 bb = *(const float4*)(a.abt + (size_t)e * DD + lane * 4);
                float4 y;
                y.x = gelu_f((v.x - m) * rs * gg.x + bb.x);
                y.y = gelu_f((v.y - m) * rs * gg.y + bb.y);
                y.z = gelu_f((v.z - m) * rs * gg.z + bb.z);
                y.w = gelu_f((v.w - m) * rs * gg.w + bb.w);
                *(float4*)&yf32[r * 260 + lane * 4] = y;
                ushort4 o4 = {f2bf(y.x), f2bf(y.y), f2bf(y.z), f2bf(y.w)};
                *(ushort4*)&Alf[r][lane * 4] = o4;
            }
            __syncthreads();
            // gate GEMM [32x128]
            f32x4 acc2[2][2];
            #pragma unroll
            for (int q = 0; q < 2; ++q) { acc2[q][0] = (f32x4){0,0,0,0}; acc2[q][1] = (f32x4){0,0,0,0}; }
            for (int k0 = 0; k0 < DD; k0 += 64) {
                #pragma unroll
                for (int i = 0; i < 4; ++i) {
                    int c = tid + 256 * i;
                    int r = c >> 3, c8 = (c & 7) * 8;
                    *(short8*)&Dl[r][c8] = *(const short8*)(a.dw1T + (size_t)r * DD + k0 + c8);
                }
                __syncthreads();
                #pragma unroll
                for (int kk = 0; kk < 64; kk += 32) {
                    #pragma unroll
                    for (int q = 0; q < 2; ++q) {
                        short8 av = *(const short8*)&Alf[16 * q + mr][k0 + kk + g * 8];
                        #pragma unroll
                        for (int u = 0; u < 2; ++u) {
                            short8 bv = *(const short8*)&Dl[16 * (2 * w + u) + mr][kk + g * 8];
                            acc2[q][u] = __builtin_amdgcn_mfma_f32_16x16x32_bf16(av, bv, acc2[q][u], 0, 0, 0);
                        }
                    }
                }
                __syncthreads();
            }
            // gate reduce
            float pv[2][4] = {};
            #pragma unroll
            for (int u = 0; u < 2; ++u) {
                int col = 32 * w + 16 * u + mr;
                float d1 = a.db1[col], d2 = a.dw2[col];
                #pragma unroll
                for (int q = 0; q < 2; ++q)
                    #pragma unroll
                    for (int r = 0; r < 4; ++r)
                        pv[q][r] += fmaxf(acc2[q][u][r] + d1, 0.f) * d2;
            }
            #pragma unroll
            for (int o = 1; o < 16; o <<= 1) {
                #pragma unroll
                for (int q = 0; q < 2; ++q)
                    #pragma unroll
                    for (int r = 0; r < 4; ++r)
                        pv[q][r] += __shfl_xor(pv[q][r], o);
            }
            if (mr == 0) {
                #pragma unroll
                for (int q = 0; q < 2; ++q)
                    #pragma unroll
                    for (int r = 0; r < 4; ++r)
                        pg[w][16 * q + 4 * g + r] = pv[q][r];
            }
            __syncthreads();
            if (tid < TM) {
                float p = pg[0][tid] + pg[1][tid] + pg[2][tid] + pg[3][tid] + a.db2[0];
                gateS[tid] = 0.8f + 0.4f / (1.f + expf(-p));
            }
            __syncthreads();
            // scatter
            int row = tid >> 3, c0 = (tid & 7) * 32;
            if (row < nv) {
                int tok = tokS[row];
                float gt = gateS[row];
                #pragma unroll
                for (int j = 0; j < 8; ++j) {
                    float4 v = *(const float4*)&yf32[row * 260 + c0 + j * 4];
                    v.x *= gt; v.y *= gt; v.z *= gt; v.w *= gt;
                    *(float4*)(a.out + (size_t)tok * DD + c0 + j * 4) = v;
                }
            }
        }
    }
}

extern "C" void kernel_launch(void* const* d_in, const int* in_sizes, int n_in,
                              void* d_out, int out_size, void* d_ws, size_t ws_size,
                              hipStream_t stream) {
    char* wsb = (char*)d_ws;
    ushort* x_ln  = (ushort*)wsb;  wsb += (size_t)NTOK * IND * 2;
    ushort* h1    = (ushort*)wsb;  wsb += (size_t)NTOK * DD2 * 2;
    ushort* enh   = (ushort*)wsb;  wsb += (size_t)NTOK * DHH * 2;
    float*  h     = (float*)wsb;   wsb += (size_t)NTOK * DD * 4;
    float*  e_pre = (float*)wsb;   wsb += (size_t)NTOK * DD * 4;
    ushort* pw1T  = (ushort*)wsb;  wsb += (size_t)DD2 * IND * 2;
    ushort* pw2T  = (ushort*)wsb;  wsb += (size_t)DD * DD2 * 2;
    ushort* fwT   = (ushort*)wsb;  wsb += (size_t)DD * DD * 2;
    ushort* aWT   = (ushort*)wsb;  wsb += (size_t)NEXP * DD * DD * 2;
    ushort* dw1T  = (ushort*)wsb;  wsb += (size_t)DHH * DD * 2;
    float*  ctail = (float*)wsb;   wsb += DD * 4;
    int*    sorted = (int*)wsb;    wsb += NTOK * 4;
    int*    tpos   = (int*)wsb;    wsb += NTILE_MAX * 4 + 4;
    int*    tcnt   = (int*)wsb;    wsb += NTILE_MAX * 4 + 4;
    int*    texp   = (int*)wsb;    wsb += NTILE_MAX * 4 + 4;
    int*    meta   = (int*)wsb;    wsb += 64;
    int*    bar    = (int*)wsb;    wsb += 64;

    KArgs a;
    a.tokens = (const float*)d_in[0];
    a.ln_g = (const float*)d_in[1];
    a.ln_b = (const float*)d_in[2];
    a.pw1 = (const float*)d_in[3];
    a.pb1 = (const float*)d_in[4];
    a.pw2 = (const float*)d_in[5];
    a.pb2 = (const float*)d_in[6];
    a.emb = (const float*)d_in[7];
    a.sw1 = (const float*)d_in[8];
    a.sb1 = (const float*)d_in[9];
    a.sw2 = (const float*)d_in[10];
    a.sb2 = (const float*)d_in[11];
    a.ew1 = (const float*)d_in[12];
    a.eb1 = (const float*)d_in[13];
    a.ew2 = (const float*)d_in[14];
    a.eb2 = (const float*)d_in[15];
    a.spw1 = (const float*)d_in[16];
    a.spb1 = (const float*)d_in[17];
    a.spw2 = (const float*)d_in[18];
    a.spb2 = (const float*)d_in[19];
    a.lw1 = (const float*)d_in[20];
    a.lb1 = (const float*)d_in[21];
    a.lw2 = (const float*)d_in[22];
    a.lb2 = (const float*)d_in[23];
    a.fw = (const float*)d_in[24];
    a.fb = (const float*)d_in[25];
    a.fg = (const float*)d_in[26];
    a.fbeta = (const float*)d_in[27];
    a.aW = (const float*)d_in[28];
    a.ab = (const float*)d_in[29];
    a.ag = (const float*)d_in[30];
    a.abt = (const float*)d_in[31];
    a.dw1 = (const float*)d_in[32];
    a.db1 = (const float*)d_in[33];
    a.dw2 = (const float*)d_in[34];
    a.db2 = (const float*)d_in[35];
    a.levels = (const int*)d_in[36];
    a.ph = (const int*)d_in[37];
    a.pw = (const int*)d_in[38];
    a.x_ln = x_ln; a.h1 = h1; a.enh = enh; a.h = h; a.e_pre = e_pre;
    a.pw1T = pw1T; a.pw2T = pw2T; a.fwT = fwT; a.aWT = aWT; a.dw1T = dw1T;
    a.ctail = ctail; a.sorted = sorted; a.tpos = tpos; a.tcnt = tcnt;
    a.texp = texp; a.meta = meta; a.bar = bar;
    a.out = (float*)d_out;

    int maxb = 0;
    hipOccupancyMaxActiveBlocksPerMultiprocessor(&maxb, k_mega, 256, 0);
    int nblk = maxb * 256;
    if (nblk > NBLK_MAX) nblk = NBLK_MAX;
    if (nblk < 2) nblk = 2;
    a.nblk = nblk;

    hipMemsetAsync(bar, 0, 64, stream);
    void* params[1] = {&a};
    hipLaunchCooperativeKernel((const void*)k_mega, dim3(nblk), dim3(256),
                               params, 0, stream);
}

// Round 11
// 70.690 us; speedup vs baseline: 5.0722x; 5.0722x over previous
//
#include <hip/hip_runtime.h>
#include <math.h>

#define NTOK 4096
#define IND 768
#define DD 256
#define DD2 512
#define DHH 128
#define NEXP 51
#define TM 32
#define NTILE_MAX 179
#define NWCONV 968

typedef __attribute__((ext_vector_type(4))) float f32x4;
typedef __attribute__((ext_vector_type(8))) short short8;

__device__ __forceinline__ float gelu_f(float x) {
    return 0.5f * x * (1.0f + erff(x * 0.70710678118654752440f));
}
__device__ __forceinline__ ushort f2bf(float x) {
    unsigned u = __float_as_uint(x);
    return (ushort)((u + 0x7fffu + ((u >> 16) & 1u)) >> 16);
}
// async global->LDS, 16B per lane; LDS dest = wave-uniform base + lane*16
__device__ __forceinline__ void gl_lds16(const ushort* g, ushort* l) {
    __builtin_amdgcn_global_load_lds(
        (const __attribute__((address_space(1))) unsigned int*)g,
        (__attribute__((address_space(3))) unsigned int*)l, 16, 0, 0);
}

// ---- fused pre-pass ----
// block 0: grouping + const-feat MLPs + ctail
// blocks [1, 1+NWCONV): weight transpose + bf16
// blocks [1+NWCONV, 1+NWCONV+NTOK/4): per-token stats, one WAVE per token
__global__ __launch_bounds__(256) void k_pre(
    const float* __restrict__ pw1, const float* __restrict__ pw2,
    const float* __restrict__ fw, const float* __restrict__ dw1,
    const float* __restrict__ aW,
    ushort* __restrict__ pw1T, ushort* __restrict__ pw2T, ushort* __restrict__ fwT,
    ushort* __restrict__ dw1T, ushort* __restrict__ aWT,
    const float* __restrict__ tokens,
    const float* __restrict__ ln_g, const float* __restrict__ ln_b,
    const float* __restrict__ sw1, const float* __restrict__ sb1,
    const float* __restrict__ sw2, const float* __restrict__ sb2,
    const float* __restrict__ ew1, const float* __restrict__ eb1,
    const float* __restrict__ ew2, const float* __restrict__ eb2,
    ushort* __restrict__ x_ln, ushort* __restrict__ enh,
    const int* __restrict__ levels,
    const float* __restrict__ spw1, const float* __restrict__ spb1,
    const float* __restrict__ spw2, const float* __restrict__ spb2,
    const float* __restrict__ lw1, const float* __restrict__ lb1,
    const float* __restrict__ lw2, const float* __restrict__ lb2,
    const int* __restrict__ ph, const int* __restrict__ pw,
    const float* __restrict__ fb,
    int* __restrict__ sorted, int* __restrict__ tpos, int* __restrict__ tcnt,
    int* __restrict__ texp, int* __restrict__ meta, float* __restrict__ ctail) {
    __shared__ float T[64][65];
    __shared__ int cnt[NEXP], cur[NEXP], offS[NEXP + 1], tileoff[NEXP + 1];
    __shared__ int expS[NTOK];
    __shared__ float hsS[64], hlS[64], cf[128];
    int t = threadIdx.x;

    if (blockIdx.x == 0) {
        if (t < NEXP) cnt[t] = 0;
        if (t < 64) {
            float p0 = (float)ph[0], p1 = (float)pw[0];
            float lvl = (float)levels[0];
            hsS[t] = fmaxf(0.f, p0 * spw1[t] + p1 * spw1[64 + t] + spb1[t]);
            hlS[t] = fmaxf(0.f, lvl * lw1[t] + lb1[t]);
        }
        __syncthreads();
        int myidx[16];
        #pragma unroll
        for (int i = 0; i < 16; ++i) {
            int n = t + i * 256;
            int id = min(max(levels[n * 2], 0), NEXP - 1);
            myidx[i] = id;
            atomicAdd(&cnt[id], 1);
        }
        if (t < 64) {
            float v = spb2[t];
            for (int j = 0; j < 64; ++j) v += hsS[j] * spw2[j * 64 + t];
            cf[t] = v;
        } else if (t < 128) {
            int k = t - 64;
            float v = lb2[k];
            for (int j = 0; j < 64; ++j) v += hlS[j] * lw2[j * 64 + k];
            cf[64 + k] = v;
        }
        __syncthreads();
        if (t == 0) {
            int a = 0, ta = 0;
            for (int e = 0; e < NEXP; ++e) {
                offS[e] = a; cur[e] = a; tileoff[e] = ta;
                ta += (cnt[e] + TM - 1) / TM;
                a += cnt[e];
            }
            offS[NEXP] = a; tileoff[NEXP] = ta;
            meta[0] = ta;
        }
        __syncthreads();
        #pragma unroll
        for (int i = 0; i < 16; ++i) {
            int n = t + i * 256;
            int p = atomicAdd(&cur[myidx[i]], 1);
            sorted[p] = n;
            expS[p] = myidx[i];
        }
        {
            float v = fb[t];
            for (int j = 0; j < 128; ++j) v += cf[j] * fw[(size_t)(128 + j) * DD + t];
            ctail[t] = v;
        }
        __syncthreads();
        #pragma unroll
        for (int i = 0; i < 16; ++i) {
            int p = t + i * 256;
            int e = expS[p];
            int rel = p - offS[e];
            if ((rel & (TM - 1)) == 0) {
                int ti = tileoff[e] + (rel / TM);
                tpos[ti] = p;
                tcnt[ti] = min(TM, offS[e + 1] - p);
                texp[ti] = e;
            }
        }
        return;
    }
    if (blockIdx.x < 1 + NWCONV) {
        int b = blockIdx.x - 1;
        const float* src; ushort* dst; int R, C;
        if (b < 96)       { src = pw1; dst = pw1T; R = IND; C = DD2; }
        else if (b < 128) { b -= 96;  src = pw2; dst = pw2T; R = DD2; C = DD; }
        else if (b < 144) { b -= 128; src = fw;  dst = fwT;  R = DD;  C = DD; }
        else if (b < 152) { b -= 144; src = dw1; dst = dw1T; R = DD;  C = DHH; }
        else { b -= 152; int e = b >> 4; b &= 15;
               src = aW + (size_t)e * DD * DD; dst = aWT + (size_t)e * DD * DD;
               R = DD; C = DD; }
        int tpc = C >> 6;
        int tr = b / tpc, tc = b - tr * tpc;
        int lr = t >> 6, lc = t & 63;
        #pragma unroll
        for (int i = 0; i < 16; ++i) {
            int r = i * 4 + lr;
            T[r][lc] = src[(size_t)(tr * 64 + r) * C + tc * 64 + lc];
        }
        __syncthreads();
        #pragma unroll
        for (int i = 0; i < 16; ++i) {
            int r = i * 4 + lr;
            dst[(size_t)(tc * 64 + r) * R + tr * 64 + lc] = f2bf(T[lc][r]);
        }
        return;
    }
    // --- per-token stats: one wave per token, no block barriers ---
    {
        int w = t >> 6, lane = t & 63;
        int n = (blockIdx.x - 1 - NWCONV) * 4 + w;
        const float* x = tokens + (size_t)n * IND;
        float v[12];
        {
            float4 va = *(const float4*)(x + lane * 12);
            float4 vb = *(const float4*)(x + lane * 12 + 4);
            float4 vc = *(const float4*)(x + lane * 12 + 8);
            v[0]=va.x; v[1]=va.y; v[2]=va.z; v[3]=va.w;
            v[4]=vb.x; v[5]=vb.y; v[6]=vb.z; v[7]=vb.w;
            v[8]=vc.x; v[9]=vc.y; v[10]=vc.z; v[11]=vc.w;
        }
        float s = 0.f, s2 = 0.f, es = 0.f;
        #pragma unroll
        for (int j = 0; j < 12; ++j) { s += v[j]; s2 += v[j] * v[j]; }
        float prev = __shfl_up(v[11], 1);
        if (lane > 0) es += fabsf(v[0] - prev);
        #pragma unroll
        for (int j = 1; j < 12; ++j) es += fabsf(v[j] - v[j - 1]);
        #pragma unroll
        for (int o = 1; o < 64; o <<= 1) {
            s  += __shfl_xor(s, o);
            s2 += __shfl_xor(s2, o);
            es += __shfl_xor(es, o);
        }
        float mean = s * (1.f / 768.f);
        float var_u = (s2 - 768.f * mean * mean) * (1.f / 767.f);
        float rstd = rsqrtf(s2 * (1.f / 768.f) - mean * mean + 1e-5f);
        float edge = es * (1.f / 767.f);
        ushort xl[12];
        #pragma unroll
        for (int j = 0; j < 12; ++j) {
            int e = lane * 12 + j;
            xl[j] = f2bf((v[j] - mean) * rstd * ln_g[e] + ln_b[e]);
        }
        ushort* xd = x_ln + (size_t)n * IND + lane * 12;
        *(ushort4*)(xd)     = *(ushort4*)&xl[0];
        *(ushort4*)(xd + 4) = *(ushort4*)&xl[4];
        *(ushort4*)(xd + 8) = *(ushort4*)&xl[8];
        // per-token MLPs: lane = hidden/output index (64-wide)
        float hs_ = fmaxf(0.f, var_u * sw1[lane] + mean * sw1[64 + lane] + sb1[lane]);
        float he_ = fmaxf(0.f, edge * ew1[lane] + eb1[lane]);
        float acc_s = sb2[lane], acc_e = eb2[lane];
        #pragma unroll 8
        for (int j = 0; j < 64; ++j) {
            float hj = __shfl(hs_, j);
            float ej = __shfl(he_, j);
            acc_s += hj * sw2[j * 64 + lane];
            acc_e += ej * ew2[j * 64 + lane];
        }
        ushort* er = enh + (size_t)n * DHH;
        er[lane] = f2bf(acc_s);
        er[64 + lane] = f2bf(acc_e);
    }
}

// ---- GEMM1: h1 = gelu(x_ln @ pw1T^T + pb1); 64x64 tile, gload_lds + XOR swizzle ----
__global__ __launch_bounds__(256) void k_gemm1(
    const ushort* __restrict__ A, const ushort* __restrict__ BT,
    const float* __restrict__ bias, ushort* __restrict__ Cb) {
    const int N = DD2, K = IND;
    __shared__ ushort Al[64][64];
    __shared__ ushort Bl[64][64];
    int tid = threadIdx.x;
    int w = tid >> 6, lane = tid & 63;
    int g = lane >> 4, mr = lane & 15;
    int bm = blockIdx.y * 64, bn = blockIdx.x * 64;
    int r8 = lane >> 3, c = lane & 7, cg = c ^ r8;   // pre-swizzled source chunk
    f32x4 acc[4];
    #pragma unroll
    for (int f = 0; f < 4; ++f) acc[f] = (f32x4){0.f, 0.f, 0.f, 0.f};
    for (int k0 = 0; k0 < K; k0 += 64) {
        #pragma unroll
        for (int i = 0; i < 2; ++i) {
            int r = 16 * w + 8 * i + r8;
            gl_lds16(A + (size_t)(bm + r) * K + k0 + cg * 8, &Al[16 * w + 8 * i][0]);
            gl_lds16(BT + (size_t)(bn + r) * K + k0 + cg * 8, &Bl[16 * w + 8 * i][0]);
        }
        asm volatile("s_waitcnt vmcnt(0)" ::: "memory");
        __syncthreads();
        #pragma unroll
        for (int kk = 0; kk < 64; kk += 32) {
            int jc = (kk >> 3) + g;
            int sw = ((jc ^ (mr & 7)) << 4);
            short8 av = *(const short8*)((const char*)&Al[0][0] + (16 * w + mr) * 128 + sw);
            #pragma unroll
            for (int f = 0; f < 4; ++f) {
                short8 bv = *(const short8*)((const char*)&Bl[0][0] + (16 * f + mr) * 128 + sw);
                acc[f] = __builtin_amdgcn_mfma_f32_16x16x32_bf16(av, bv, acc[f], 0, 0, 0);
            }
        }
        __syncthreads();
    }
    #pragma unroll
    for (int f = 0; f < 4; ++f) {
        int col = bn + 16 * f + mr;
        float bv = bias[col];
        #pragma unroll
        for (int r = 0; r < 4; ++r) {
            int row = bm + 16 * w + 4 * g + r;
            Cb[(size_t)row * N + col] = f2bf(gelu_f(acc[f][r] + bv));
        }
    }
}

// ---- fused GEMM2+GEMM3, gload_lds + swizzle ----
__global__ __launch_bounds__(256) void k_mid(
    const ushort* __restrict__ h1, const ushort* __restrict__ pw2T,
    const float* __restrict__ pb2, const int* __restrict__ levels,
    const float* __restrict__ emb, float* __restrict__ h,
    const ushort* __restrict__ enh, const ushort* __restrict__ fwT,
    const float* __restrict__ ctail, float* __restrict__ e_pre) {
    __shared__ ushort Al[64][64];
    __shared__ ushort Bl[64][64];
    int by = blockIdx.y;
    const ushort* A; const ushort* BT; const float* bias; float* Cf;
    int K, sA, sB, epi, bm;
    if (by < 64) { A = h1; BT = pw2T; bias = pb2; Cf = h; K = DD2; sA = DD2; sB = DD2; epi = 2; bm = by * 64; }
    else         { A = enh; BT = fwT; bias = ctail; Cf = e_pre; K = DHH; sA = DHH; sB = DD; epi = 0; bm = (by - 64) * 64; }
    int tid = threadIdx.x;
    int w = tid >> 6, lane = tid & 63;
    int g = lane >> 4, mr = lane & 15;
    int bn = blockIdx.x * 64;
    int r8 = lane >> 3, c = lane & 7, cg = c ^ r8;
    f32x4 acc[4];
    #pragma unroll
    for (int f = 0; f < 4; ++f) acc[f] = (f32x4){0.f, 0.f, 0.f, 0.f};
    for (int k0 = 0; k0 < K; k0 += 64) {
        #pragma unroll
        for (int i = 0; i < 2; ++i) {
            int r = 16 * w + 8 * i + r8;
            gl_lds16(A + (size_t)(bm + r) * sA + k0 + cg * 8, &Al[16 * w + 8 * i][0]);
            gl_lds16(BT + (size_t)(bn + r) * sB + k0 + cg * 8, &Bl[16 * w + 8 * i][0]);
        }
        asm volatile("s_waitcnt vmcnt(0)" ::: "memory");
        __syncthreads();
        #pragma unroll
        for (int kk = 0; kk < 64; kk += 32) {
            int jc = (kk >> 3) + g;
            int sw = ((jc ^ (mr & 7)) << 4);
            short8 av = *(const short8*)((const char*)&Al[0][0] + (16 * w + mr) * 128 + sw);
            #pragma unroll
            for (int f = 0; f < 4; ++f) {
                short8 bv = *(const short8*)((const char*)&Bl[0][0] + (16 * f + mr) * 128 + sw);
                acc[f] = __builtin_amdgcn_mfma_f32_16x16x32_bf16(av, bv, acc[f], 0, 0, 0);
            }
        }
        __syncthreads();
    }
    #pragma unroll
    for (int f = 0; f < 4; ++f) {
        int col = bn + 16 * f + mr;
        float bv = bias[col];
        #pragma unroll
        for (int r = 0; r < 4; ++r) {
            int row = bm + 16 * w + 4 * g + r;
            float v = acc[f][r] + bv;
            if (epi == 2) {
                int id = min(max(levels[row * 2], 0), NEXP - 1);
                v += emb[(size_t)id * DD + col];
            }
            Cf[(size_t)row * DD + col] = v;
        }
    }
}

// ---- fully fused adapter, 8 waves/block (round-8 proven body) ----
__global__ __launch_bounds__(512) void k_adapterF(
    const float* __restrict__ h, const float* __restrict__ e_pre,
    const float* __restrict__ fg, const float* __restrict__ fbeta,
    const ushort* __restrict__ aWT, const float* __restrict__ ab,
    const float* __restrict__ ag, const float* __restrict__ abt,
    const ushort* __restrict__ dw1T, const float* __restrict__ db1,
    const float* __restrict__ dw2, const float* __restrict__ db2,
    const int* __restrict__ sorted, const int* __restrict__ tpos,
    const int* __restrict__ tcnt, const int* __restrict__ texp,
    const int* __restrict__ meta, float* __restrict__ out) {
    __shared__ __align__(16) ushort Alf[TM][264];
    __shared__ __align__(16) char BlRaw[256 * 72 * 2];
    __shared__ __align__(16) ushort Dl[DHH][72];
    __shared__ int tokS[TM];
    __shared__ float gateS[TM];
    __shared__ float pg[4][TM];
    int b = blockIdx.x;
    if (b >= meta[0]) return;
    int tid = threadIdx.x, w = tid >> 6, lane = tid & 63;
    int g = lane >> 4, mr = lane & 15;
    int e = texp[b], base = tpos[b], nv = tcnt[b];
    if (tid < TM) tokS[tid] = sorted[base + min(tid, nv - 1)];
    __syncthreads();
    #pragma unroll
    for (int i = 0; i < 4; ++i) {
        int r = w * 4 + i;
        int tok = tokS[r];
        float4 e4 = *(const float4*)(e_pre + (size_t)tok * DD + lane * 4);
        float s = e4.x + e4.y + e4.z + e4.w;
        float s2 = e4.x * e4.x + e4.y * e4.y + e4.z * e4.z + e4.w * e4.w;
        #pragma unroll
        for (int o = 1; o < 64; o <<= 1) { s += __shfl_xor(s, o); s2 += __shfl_xor(s2, o); }
        float m = s * (1.f / 256.f);
        float rs = rsqrtf(s2 * (1.f / 256.f) - m * m + 1e-5f);
        float4 h4 = *(const float4*)(h + (size_t)tok * DD + lane * 4);
        float4 g4 = *(const float4*)(fg + lane * 4);
        float4 b4 = *(const float4*)(fbeta + lane * 4);
        ushort4 o4;
        o4.x = f2bf(h4.x + 0.3f * gelu_f((e4.x - m) * rs * g4.x + b4.x));
        o4.y = f2bf(h4.y + 0.3f * gelu_f((e4.y - m) * rs * g4.y + b4.y));
        o4.z = f2bf(h4.z + 0.3f * gelu_f((e4.z - m) * rs * g4.z + b4.z));
        o4.w = f2bf(h4.w + 0.3f * gelu_f((e4.w - m) * rs * g4.w + b4.w));
        *(ushort4*)&Alf[r][lane * 4] = o4;
    }
    __syncthreads();
    ushort* Bl = (ushort*)BlRaw;
    const ushort* We = aWT + (size_t)e * DD * DD;
    int mt = w & 1, cb = 64 * (w >> 1);
    f32x4 acc[4];
    #pragma unroll
    for (int q = 0; q < 4; ++q) acc[q] = (f32x4){0.f, 0.f, 0.f, 0.f};
    for (int k0 = 0; k0 < DD; k0 += 64) {
        #pragma unroll
        for (int i = 0; i < 4; ++i) {
            int cdx = tid + 512 * i;
            int r = cdx >> 3, c8 = (cdx & 7) * 8;
            *(short8*)&Bl[r * 72 + c8] = *(const short8*)(We + (size_t)r * DD + k0 + c8);
        }
        __syncthreads();
        #pragma unroll
        for (int kk = 0; kk < 64; kk += 32) {
            short8 av = *(const short8*)&Alf[16 * mt + mr][k0 + kk + g * 8];
            #pragma unroll
            for (int q = 0; q < 4; ++q) {
                short8 bv = *(const short8*)&Bl[(cb + 16 * q + mr) * 72 + kk + g * 8];
                acc[q] = __builtin_amdgcn_mfma_f32_16x16x32_bf16(av, bv, acc[q], 0, 0, 0);
            }
        }
        __syncthreads();
    }
    float* yf32 = (float*)BlRaw;
    #pragma unroll
    for (int q = 0; q < 4; ++q) {
        int col = cb + 16 * q + mr;
        float abv = ab[(size_t)e * DD + col];
        #pragma unroll
        for (int r = 0; r < 4; ++r) {
            int row = 16 * mt + 4 * g + r;
            yf32[row * 260 + col] = acc[q][r] + abv;
        }
    }
    __syncthreads();
    #pragma unroll
    for (int i = 0; i < 4; ++i) {
        int r = w * 4 + i;
        float4 v = *(const float4*)&yf32[r * 260 + lane * 4];
        float s = v.x + v.y + v.z + v.w;
        float s2 = v.x * v.x + v.y * v.y + v.z * v.z + v.w * v.w;
        #pragma unroll
        for (int o = 1; o < 64; o <<= 1) { s += __shfl_xor(s, o); s2 += __shfl_xor(s2, o); }
        float m = s * (1.f / 256.f);
        float rs = rsqrtf(s2 * (1.f / 256.f) - m * m + 1e-5f);
        float4 gg = *(const float4*)(ag + (size_t)e * DD + lane * 4);
        float4 bb = *(const float4*)(abt + (size_t)e * DD + lane * 4);
        float4 y;
        y.x = gelu_f((v.x - m) * rs * gg.x + bb.x);
        y.y = gelu_f((v.y - m) * rs * gg.y + bb.y);
        y.z = gelu_f((v.z - m) * rs * gg.z + bb.z);
        y.w = gelu_f((v.w - m) * rs * gg.w + bb.w);
        *(float4*)&yf32[r * 260 + lane * 4] = y;
        ushort4 o4 = {f2bf(y.x), f2bf(y.y), f2bf(y.z), f2bf(y.w)};
        *(ushort4*)&Alf[r][lane * 4] = o4;
    }
    __syncthreads();
    f32x4 acc2[2];
    acc2[0] = (f32x4){0.f, 0.f, 0.f, 0.f};
    acc2[1] = (f32x4){0.f, 0.f, 0.f, 0.f};
    for (int k0 = 0; k0 < DD; k0 += 64) {
        #pragma unroll
        for (int i = 0; i < 2; ++i) {
            int cdx = tid + 512 * i;
            int r = cdx >> 3, c8 = (cdx & 7) * 8;
            *(short8*)&Dl[r][c8] = *(const short8*)(dw1T + (size_t)r * DD + k0 + c8);
        }
        __syncthreads();
        #pragma unroll
        for (int kk = 0; kk < 64; kk += 32) {
            short8 av = *(const short8*)&Alf[16 * mt + mr][k0 + kk + g * 8];
            #pragma unroll
            for (int q = 0; q < 2; ++q) {
                short8 bv = *(const short8*)&Dl[16 * (2 * (w >> 1) + q) + mr][kk + g * 8];
                acc2[q] = __builtin_amdgcn_mfma_f32_16x16x32_bf16(av, bv, acc2[q], 0, 0, 0);
            }
        }
        __syncthreads();
    }
    float pv[4] = {0.f, 0.f, 0.f, 0.f};
    #pragma unroll
    for (int q = 0; q < 2; ++q) {
        int col = 32 * (w >> 1) + 16 * q + mr;
        float d1 = db1[col], d2 = dw2[col];
        #pragma unroll
        for (int r = 0; r < 4; ++r)
            pv[r] += fmaxf(acc2[q][r] + d1, 0.f) * d2;
    }
    #pragma unroll
    for (int o = 1; o < 16; o <<= 1) {
        #pragma unroll
        for (int r = 0; r < 4; ++r) pv[r] += __shfl_xor(pv[r], o);
    }
    if (mr == 0) {
        #pragma unroll
        for (int r = 0; r < 4; ++r)
            pg[w >> 1][16 * mt + 4 * g + r] = pv[r];
    }
    __syncthreads();
    if (tid < TM) {
        float p = pg[0][tid] + pg[1][tid] + pg[2][tid] + pg[3][tid] + db2[0];
        gateS[tid] = 0.8f + 0.4f / (1.f + expf(-p));
    }
    __syncthreads();
    {
        int row = tid >> 4, c0 = (tid & 15) * 16;
        if (row < nv) {
            int tok = tokS[row];
            float gt = gateS[row];
            #pragma unroll
            for (int j = 0; j < 4; ++j) {
                float4 v = *(const float4*)&yf32[row * 260 + c0 + j * 4];
                v.x *= gt; v.y *= gt; v.z *= gt; v.w *= gt;
                *(float4*)(out + (size_t)tok * DD + c0 + j * 4) = v;
            }
        }
    }
}

extern "C" void kernel_launch(void* const* d_in, const int* in_sizes, int n_in,
                              void* d_out, int out_size, void* d_ws, size_t ws_size,
                              hipStream_t stream) {
    const float* tokens = (const float*)d_in[0];
    const float* ln_g = (const float*)d_in[1];
    const float* ln_b = (const float*)d_in[2];
    const float* pw1 = (const float*)d_in[3];
    const float* pb1 = (const float*)d_in[4];
    const float* pw2 = (const float*)d_in[5];
    const float* pb2 = (const float*)d_in[6];
    const float* emb = (const float*)d_in[7];
    const float* sw1 = (const float*)d_in[8];
    const float* sb1 = (const float*)d_in[9];
    const float* sw2 = (const float*)d_in[10];
    const float* sb2 = (const float*)d_in[11];
    const float* ew1 = (const float*)d_in[12];
    const float* eb1 = (const float*)d_in[13];
    const float* ew2 = (const float*)d_in[14];
    const float* eb2 = (const float*)d_in[15];
    const float* spw1 = (const float*)d_in[16];
    const float* spb1 = (const float*)d_in[17];
    const float* spw2 = (const float*)d_in[18];
    const float* spb2 = (const float*)d_in[19];
    const float* lw1 = (const float*)d_in[20];
    const float* lb1 = (const float*)d_in[21];
    const float* lw2 = (const float*)d_in[22];
    const float* lb2 = (const float*)d_in[23];
    const float* fw = (const float*)d_in[24];
    const float* fb = (const float*)d_in[25];
    const float* fg = (const float*)d_in[26];
    const float* fbeta = (const float*)d_in[27];
    const float* aW = (const float*)d_in[28];
    const float* ab = (const float*)d_in[29];
    const float* ag = (const float*)d_in[30];
    const float* abt = (const float*)d_in[31];
    const float* dw1 = (const float*)d_in[32];
    const float* db1 = (const float*)d_in[33];
    const float* dw2 = (const float*)d_in[34];
    const float* db2 = (const float*)d_in[35];
    const int* levels = (const int*)d_in[36];
    const int* ph = (const int*)d_in[37];
    const int* pw = (const int*)d_in[38];
    float* outp = (float*)d_out;

    char* wsb = (char*)d_ws;
    ushort* x_ln  = (ushort*)wsb;  wsb += (size_t)NTOK * IND * 2;
    ushort* h1    = (ushort*)wsb;  wsb += (size_t)NTOK * DD2 * 2;
    ushort* enh   = (ushort*)wsb;  wsb += (size_t)NTOK * DHH * 2;
    float*  h     = (float*)wsb;   wsb += (size_t)NTOK * DD * 4;
    float*  e_pre = (float*)wsb;   wsb += (size_t)NTOK * DD * 4;
    ushort* pw1T  = (ushort*)wsb;  wsb += (size_t)DD2 * IND * 2;
    ushort* pw2T  = (ushort*)wsb;  wsb += (size_t)DD * DD2 * 2;
    ushort* fwT   = (ushort*)wsb;  wsb += (size_t)DD * DD * 2;
    ushort* aWT   = (ushort*)wsb;  wsb += (size_t)NEXP * DD * DD * 2;
    ushort* dw1T  = (ushort*)wsb;  wsb += (size_t)DHH * DD * 2;
    float*  ctail = (float*)wsb;   wsb += DD * 4;
    int*    sorted = (int*)wsb;    wsb += NTOK * 4;
    int*    tpos   = (int*)wsb;    wsb += NTILE_MAX * 4 + 4;
    int*    tcnt   = (int*)wsb;    wsb += NTILE_MAX * 4 + 4;
    int*    texp   = (int*)wsb;    wsb += NTILE_MAX * 4 + 4;
    int*    meta   = (int*)wsb;    wsb += 64;

    k_pre<<<1 + NWCONV + NTOK / 4, 256, 0, stream>>>(
        pw1, pw2, fw, dw1, aW, pw1T, pw2T, fwT, dw1T, aWT,
        tokens, ln_g, ln_b, sw1, sb1, sw2, sb2, ew1, eb1, ew2, eb2,
        x_ln, enh, levels,
        spw1, spb1, spw2, spb2, lw1, lb1, lw2, lb2, ph, pw, fb,
        sorted, tpos, tcnt, texp, meta, ctail);
    k_gemm1<<<dim3(DD2 / 64, NTOK / 64), 256, 0, stream>>>(x_ln, pw1T, pb1, h1);
    k_mid<<<dim3(DD / 64, 128), 256, 0, stream>>>(
        h1, pw2T, pb2, levels, emb, h, enh, fwT, ctail, e_pre);
    k_adapterF<<<NTILE_MAX, 512, 0, stream>>>(
        h, e_pre, fg, fbeta, aWT, ab, ag, abt, dw1T, db1, dw2, db2,
        sorted, tpos, tcnt, texp, meta, outp);
}

// Round 12
// 70.168 us; speedup vs baseline: 5.1100x; 1.0074x over previous
//
#include <hip/hip_runtime.h>
#include <math.h>

#define NTOK 4096
#define IND 768
#define DD 256
#define DD2 512
#define DHH 128
#define NEXP 51
#define TM 16
#define NTILE_MAX 312
#define NWCONV 968

typedef __attribute__((ext_vector_type(4))) float f32x4;
typedef __attribute__((ext_vector_type(8))) short short8;

__device__ __forceinline__ float gelu_f(float x) {
    return 0.5f * x * (1.0f + erff(x * 0.70710678118654752440f));
}
__device__ __forceinline__ ushort f2bf(float x) {
    unsigned u = __float_as_uint(x);
    return (ushort)((u + 0x7fffu + ((u >> 16) & 1u)) >> 16);
}
// async global->LDS, 16B/lane; LDS dest = wave-uniform base + lane*16
__device__ __forceinline__ void gl_lds16(const ushort* g, ushort* l) {
    __builtin_amdgcn_global_load_lds(
        (const __attribute__((address_space(1))) unsigned int*)g,
        (__attribute__((address_space(3))) unsigned int*)l, 16, 0, 0);
}

// ---- fused pre-pass (unchanged from round 11 except TM=16 tile build) ----
__global__ __launch_bounds__(256) void k_pre(
    const float* __restrict__ pw1, const float* __restrict__ pw2,
    const float* __restrict__ fw, const float* __restrict__ dw1,
    const float* __restrict__ aW,
    ushort* __restrict__ pw1T, ushort* __restrict__ pw2T, ushort* __restrict__ fwT,
    ushort* __restrict__ dw1T, ushort* __restrict__ aWT,
    const float* __restrict__ tokens,
    const float* __restrict__ ln_g, const float* __restrict__ ln_b,
    const float* __restrict__ sw1, const float* __restrict__ sb1,
    const float* __restrict__ sw2, const float* __restrict__ sb2,
    const float* __restrict__ ew1, const float* __restrict__ eb1,
    const float* __restrict__ ew2, const float* __restrict__ eb2,
    ushort* __restrict__ x_ln, ushort* __restrict__ enh,
    const int* __restrict__ levels,
    const float* __restrict__ spw1, const float* __restrict__ spb1,
    const float* __restrict__ spw2, const float* __restrict__ spb2,
    const float* __restrict__ lw1, const float* __restrict__ lb1,
    const float* __restrict__ lw2, const float* __restrict__ lb2,
    const int* __restrict__ ph, const int* __restrict__ pw,
    const float* __restrict__ fb,
    int* __restrict__ sorted, int* __restrict__ tpos, int* __restrict__ tcnt,
    int* __restrict__ texp, int* __restrict__ meta, float* __restrict__ ctail) {
    __shared__ float T[64][65];
    __shared__ int cnt[NEXP], cur[NEXP], offS[NEXP + 1], tileoff[NEXP + 1];
    __shared__ int expS[NTOK];
    __shared__ float hsS[64], hlS[64], cf[128];
    int t = threadIdx.x;

    if (blockIdx.x == 0) {
        if (t < NEXP) cnt[t] = 0;
        if (t < 64) {
            float p0 = (float)ph[0], p1 = (float)pw[0];
            float lvl = (float)levels[0];
            hsS[t] = fmaxf(0.f, p0 * spw1[t] + p1 * spw1[64 + t] + spb1[t]);
            hlS[t] = fmaxf(0.f, lvl * lw1[t] + lb1[t]);
        }
        __syncthreads();
        int myidx[16];
        #pragma unroll
        for (int i = 0; i < 16; ++i) {
            int n = t + i * 256;
            int id = min(max(levels[n * 2], 0), NEXP - 1);
            myidx[i] = id;
            atomicAdd(&cnt[id], 1);
        }
        if (t < 64) {
            float v = spb2[t];
            for (int j = 0; j < 64; ++j) v += hsS[j] * spw2[j * 64 + t];
            cf[t] = v;
        } else if (t < 128) {
            int k = t - 64;
            float v = lb2[k];
            for (int j = 0; j < 64; ++j) v += hlS[j] * lw2[j * 64 + k];
            cf[64 + k] = v;
        }
        __syncthreads();
        if (t == 0) {
            int a = 0, ta = 0;
            for (int e = 0; e < NEXP; ++e) {
                offS[e] = a; cur[e] = a; tileoff[e] = ta;
                ta += (cnt[e] + TM - 1) / TM;
                a += cnt[e];
            }
            offS[NEXP] = a; tileoff[NEXP] = ta;
            meta[0] = ta;
        }
        __syncthreads();
        #pragma unroll
        for (int i = 0; i < 16; ++i) {
            int n = t + i * 256;
            int p = atomicAdd(&cur[myidx[i]], 1);
            sorted[p] = n;
            expS[p] = myidx[i];
        }
        {
            float v = fb[t];
            for (int j = 0; j < 128; ++j) v += cf[j] * fw[(size_t)(128 + j) * DD + t];
            ctail[t] = v;
        }
        __syncthreads();
        #pragma unroll
        for (int i = 0; i < 16; ++i) {
            int p = t + i * 256;
            int e = expS[p];
            int rel = p - offS[e];
            if ((rel & (TM - 1)) == 0) {
                int ti = tileoff[e] + (rel / TM);
                tpos[ti] = p;
                tcnt[ti] = min(TM, offS[e + 1] - p);
                texp[ti] = e;
            }
        }
        return;
    }
    if (blockIdx.x < 1 + NWCONV) {
        int b = blockIdx.x - 1;
        const float* src; ushort* dst; int R, C;
        if (b < 96)       { src = pw1; dst = pw1T; R = IND; C = DD2; }
        else if (b < 128) { b -= 96;  src = pw2; dst = pw2T; R = DD2; C = DD; }
        else if (b < 144) { b -= 128; src = fw;  dst = fwT;  R = DD;  C = DD; }
        else if (b < 152) { b -= 144; src = dw1; dst = dw1T; R = DD;  C = DHH; }
        else { b -= 152; int e = b >> 4; b &= 15;
               src = aW + (size_t)e * DD * DD; dst = aWT + (size_t)e * DD * DD;
               R = DD; C = DD; }
        int tpc = C >> 6;
        int tr = b / tpc, tc = b - tr * tpc;
        int lr = t >> 6, lc = t & 63;
        #pragma unroll
        for (int i = 0; i < 16; ++i) {
            int r = i * 4 + lr;
            T[r][lc] = src[(size_t)(tr * 64 + r) * C + tc * 64 + lc];
        }
        __syncthreads();
        #pragma unroll
        for (int i = 0; i < 16; ++i) {
            int r = i * 4 + lr;
            dst[(size_t)(tc * 64 + r) * R + tr * 64 + lc] = f2bf(T[lc][r]);
        }
        return;
    }
    // per-token stats: one wave per token
    {
        int w = t >> 6, lane = t & 63;
        int n = (blockIdx.x - 1 - NWCONV) * 4 + w;
        const float* x = tokens + (size_t)n * IND;
        float v[12];
        {
            float4 va = *(const float4*)(x + lane * 12);
            float4 vb = *(const float4*)(x + lane * 12 + 4);
            float4 vc = *(const float4*)(x + lane * 12 + 8);
            v[0]=va.x; v[1]=va.y; v[2]=va.z; v[3]=va.w;
            v[4]=vb.x; v[5]=vb.y; v[6]=vb.z; v[7]=vb.w;
            v[8]=vc.x; v[9]=vc.y; v[10]=vc.z; v[11]=vc.w;
        }
        float s = 0.f, s2 = 0.f, es = 0.f;
        #pragma unroll
        for (int j = 0; j < 12; ++j) { s += v[j]; s2 += v[j] * v[j]; }
        float prev = __shfl_up(v[11], 1);
        if (lane > 0) es += fabsf(v[0] - prev);
        #pragma unroll
        for (int j = 1; j < 12; ++j) es += fabsf(v[j] - v[j - 1]);
        #pragma unroll
        for (int o = 1; o < 64; o <<= 1) {
            s  += __shfl_xor(s, o);
            s2 += __shfl_xor(s2, o);
            es += __shfl_xor(es, o);
        }
        float mean = s * (1.f / 768.f);
        float var_u = (s2 - 768.f * mean * mean) * (1.f / 767.f);
        float rstd = rsqrtf(s2 * (1.f / 768.f) - mean * mean + 1e-5f);
        float edge = es * (1.f / 767.f);
        ushort xl[12];
        #pragma unroll
        for (int j = 0; j < 12; ++j) {
            int e = lane * 12 + j;
            xl[j] = f2bf((v[j] - mean) * rstd * ln_g[e] + ln_b[e]);
        }
        ushort* xd = x_ln + (size_t)n * IND + lane * 12;
        *(ushort4*)(xd)     = *(ushort4*)&xl[0];
        *(ushort4*)(xd + 4) = *(ushort4*)&xl[4];
        *(ushort4*)(xd + 8) = *(ushort4*)&xl[8];
        float hs_ = fmaxf(0.f, var_u * sw1[lane] + mean * sw1[64 + lane] + sb1[lane]);
        float he_ = fmaxf(0.f, edge * ew1[lane] + eb1[lane]);
        float acc_s = sb2[lane], acc_e = eb2[lane];
        #pragma unroll 8
        for (int j = 0; j < 64; ++j) {
            float hj = __shfl(hs_, j);
            float ej = __shfl(he_, j);
            acc_s += hj * sw2[j * 64 + lane];
            acc_e += ej * ew2[j * 64 + lane];
        }
        ushort* er = enh + (size_t)n * DHH;
        er[lane] = f2bf(acc_s);
        er[64 + lane] = f2bf(acc_e);
    }
}

// ---- GEMM1: h1 = gelu(x_ln @ pw1T^T + pb1); 128x64 tile, 8 waves, gload_lds+swizzle ----
__global__ __launch_bounds__(512) void k_gemm1(
    const ushort* __restrict__ A, const ushort* __restrict__ BT,
    const float* __restrict__ bias, ushort* __restrict__ Cb) {
    const int N = DD2, K = IND;
    __shared__ ushort Al[128][64];
    __shared__ ushort Bl[64][64];
    int tid = threadIdx.x;
    int w = tid >> 6, lane = tid & 63;
    int g = lane >> 4, mr = lane & 15;
    int mq = w >> 1, nq = w & 1;
    int bm = blockIdx.y * 128, bn = blockIdx.x * 64;
    int r8 = lane >> 3, c = lane & 7, cg = c ^ r8;
    f32x4 acc[2][2];
    #pragma unroll
    for (int im = 0; im < 2; ++im)
        #pragma unroll
        for (int in = 0; in < 2; ++in) acc[im][in] = (f32x4){0.f, 0.f, 0.f, 0.f};
    for (int k0 = 0; k0 < K; k0 += 64) {
        #pragma unroll
        for (int i = 0; i < 2; ++i) {
            int r = 16 * w + 8 * i + r8;
            gl_lds16(A + (size_t)(bm + r) * K + k0 + cg * 8, &Al[16 * w + 8 * i][0]);
        }
        {
            int r = 8 * w + r8;
            gl_lds16(BT + (size_t)(bn + r) * K + k0 + cg * 8, &Bl[8 * w][0]);
        }
        asm volatile("s_waitcnt vmcnt(0)" ::: "memory");
        __syncthreads();
        #pragma unroll
        for (int kk = 0; kk < 64; kk += 32) {
            int jc = (kk >> 3) + g;
            int sw = ((jc ^ (mr & 7)) << 4);
            #pragma unroll
            for (int im = 0; im < 2; ++im) {
                short8 av = *(const short8*)((const char*)&Al[0][0] + (32 * mq + 16 * im + mr) * 128 + sw);
                #pragma unroll
                for (int in = 0; in < 2; ++in) {
                    short8 bv = *(const short8*)((const char*)&Bl[0][0] + (32 * nq + 16 * in + mr) * 128 + sw);
                    acc[im][in] = __builtin_amdgcn_mfma_f32_16x16x32_bf16(av, bv, acc[im][in], 0, 0, 0);
                }
            }
        }
        __syncthreads();
    }
    #pragma unroll
    for (int im = 0; im < 2; ++im) {
        #pragma unroll
        for (int in = 0; in < 2; ++in) {
            int col = bn + 32 * nq + 16 * in + mr;
            float bv = bias[col];
            #pragma unroll
            for (int r = 0; r < 4; ++r) {
                int row = bm + 32 * mq + 16 * im + 4 * g + r;
                Cb[(size_t)row * N + col] = f2bf(gelu_f(acc[im][in][r] + bv));
            }
        }
    }
}

// ---- fused GEMM2+GEMM3, 64x64, gload_lds + swizzle (round-11 proven) ----
__global__ __launch_bounds__(256) void k_mid(
    const ushort* __restrict__ h1, const ushort* __restrict__ pw2T,
    const float* __restrict__ pb2, const int* __restrict__ levels,
    const float* __restrict__ emb, float* __restrict__ h,
    const ushort* __restrict__ enh, const ushort* __restrict__ fwT,
    const float* __restrict__ ctail, float* __restrict__ e_pre) {
    __shared__ ushort Al[64][64];
    __shared__ ushort Bl[64][64];
    int by = blockIdx.y;
    const ushort* A; const ushort* BT; const float* bias; float* Cf;
    int K, sA, sB, epi, bm;
    if (by < 64) { A = h1; BT = pw2T; bias = pb2; Cf = h; K = DD2; sA = DD2; sB = DD2; epi = 2; bm = by * 64; }
    else         { A = enh; BT = fwT; bias = ctail; Cf = e_pre; K = DHH; sA = DHH; sB = DD; epi = 0; bm = (by - 64) * 64; }
    int tid = threadIdx.x;
    int w = tid >> 6, lane = tid & 63;
    int g = lane >> 4, mr = lane & 15;
    int bn = blockIdx.x * 64;
    int r8 = lane >> 3, c = lane & 7, cg = c ^ r8;
    f32x4 acc[4];
    #pragma unroll
    for (int f = 0; f < 4; ++f) acc[f] = (f32x4){0.f, 0.f, 0.f, 0.f};
    for (int k0 = 0; k0 < K; k0 += 64) {
        #pragma unroll
        for (int i = 0; i < 2; ++i) {
            int r = 16 * w + 8 * i + r8;
            gl_lds16(A + (size_t)(bm + r) * sA + k0 + cg * 8, &Al[16 * w + 8 * i][0]);
            gl_lds16(BT + (size_t)(bn + r) * sB + k0 + cg * 8, &Bl[16 * w + 8 * i][0]);
        }
        asm volatile("s_waitcnt vmcnt(0)" ::: "memory");
        __syncthreads();
        #pragma unroll
        for (int kk = 0; kk < 64; kk += 32) {
            int jc = (kk >> 3) + g;
            int sw = ((jc ^ (mr & 7)) << 4);
            short8 av = *(const short8*)((const char*)&Al[0][0] + (16 * w + mr) * 128 + sw);
            #pragma unroll
            for (int f = 0; f < 4; ++f) {
                short8 bv = *(const short8*)((const char*)&Bl[0][0] + (16 * f + mr) * 128 + sw);
                acc[f] = __builtin_amdgcn_mfma_f32_16x16x32_bf16(av, bv, acc[f], 0, 0, 0);
            }
        }
        __syncthreads();
    }
    #pragma unroll
    for (int f = 0; f < 4; ++f) {
        int col = bn + 16 * f + mr;
        float bv = bias[col];
        #pragma unroll
        for (int r = 0; r < 4; ++r) {
            int row = bm + 16 * w + 4 * g + r;
            float v = acc[f][r] + bv;
            if (epi == 2) {
                int id = min(max(levels[row * 2], 0), NEXP - 1);
                v += emb[(size_t)id * DD + col];
            }
            Cf[(size_t)row * DD + col] = v;
        }
    }
}

// ---- fused adapter: TM=16 tokens, 256 threads (4 waves), gload_lds-staged B/dw1 ----
__global__ __launch_bounds__(256) void k_adapterF(
    const float* __restrict__ h, const float* __restrict__ e_pre,
    const float* __restrict__ fg, const float* __restrict__ fbeta,
    const ushort* __restrict__ aWT, const float* __restrict__ ab,
    const float* __restrict__ ag, const float* __restrict__ abt,
    const ushort* __restrict__ dw1T, const float* __restrict__ db1,
    const float* __restrict__ dw2, const float* __restrict__ db2,
    const int* __restrict__ sorted, const int* __restrict__ tpos,
    const int* __restrict__ tcnt, const int* __restrict__ texp,
    const int* __restrict__ meta, float* __restrict__ out) {
    __shared__ __align__(16) ushort Alf[TM][264];     // hfull bf16, later y bf16
    __shared__ __align__(16) ushort Bl[256][64];      // aW k-chunk; later yf32[16][260]
    __shared__ __align__(16) ushort Dl[DHH][64];      // dw1 k-chunk
    __shared__ int tokS[TM];
    __shared__ float gateS[TM];
    __shared__ float pg[4][TM];
    int b = blockIdx.x;
    if (b >= meta[0]) return;
    int tid = threadIdx.x, w = tid >> 6, lane = tid & 63;
    int g = lane >> 4, mr = lane & 15;
    int r8 = lane >> 3, c = lane & 7, cg = c ^ r8;
    int e = texp[b], base = tpos[b], nv = tcnt[b];
    if (tid < TM) tokS[tid] = sorted[base + min(tid, nv - 1)];
    __syncthreads();
    // phase 1: hfull = h + 0.3*gelu(LN(e_pre)) -> Alf; wave per 4 rows
    #pragma unroll
    for (int i = 0; i < 4; ++i) {
        int r = w * 4 + i;
        int tok = tokS[r];
        float4 e4 = *(const float4*)(e_pre + (size_t)tok * DD + lane * 4);
        float s = e4.x + e4.y + e4.z + e4.w;
        float s2 = e4.x * e4.x + e4.y * e4.y + e4.z * e4.z + e4.w * e4.w;
        #pragma unroll
        for (int o = 1; o < 64; o <<= 1) { s += __shfl_xor(s, o); s2 += __shfl_xor(s2, o); }
        float m = s * (1.f / 256.f);
        float rs = rsqrtf(s2 * (1.f / 256.f) - m * m + 1e-5f);
        float4 h4 = *(const float4*)(h + (size_t)tok * DD + lane * 4);
        float4 g4 = *(const float4*)(fg + lane * 4);
        float4 b4 = *(const float4*)(fbeta + lane * 4);
        ushort4 o4;
        o4.x = f2bf(h4.x + 0.3f * gelu_f((e4.x - m) * rs * g4.x + b4.x));
        o4.y = f2bf(h4.y + 0.3f * gelu_f((e4.y - m) * rs * g4.y + b4.y));
        o4.z = f2bf(h4.z + 0.3f * gelu_f((e4.z - m) * rs * g4.z + b4.z));
        o4.w = f2bf(h4.w + 0.3f * gelu_f((e4.w - m) * rs * g4.w + b4.w));
        *(ushort4*)&Alf[r][lane * 4] = o4;
    }
    __syncthreads();
    // phase 2: expert GEMM [16 x 256]; wave w -> cols 64w..64w+63 (4 frags)
    const ushort* We = aWT + (size_t)e * DD * DD;
    f32x4 acc[4];
    #pragma unroll
    for (int q = 0; q < 4; ++q) acc[q] = (f32x4){0.f, 0.f, 0.f, 0.f};
    for (int k0 = 0; k0 < DD; k0 += 64) {
        #pragma unroll
        for (int i = 0; i < 8; ++i) {
            int r = 64 * w + 8 * i + r8;
            gl_lds16(We + (size_t)r * DD + k0 + cg * 8, &Bl[64 * w + 8 * i][0]);
        }
        asm volatile("s_waitcnt vmcnt(0)" ::: "memory");
        __syncthreads();
        #pragma unroll
        for (int kk = 0; kk < 64; kk += 32) {
            int jc = (kk >> 3) + g;
            int sw = ((jc ^ (mr & 7)) << 4);
            short8 av = *(const short8*)&Alf[mr][k0 + kk + g * 8];
            #pragma unroll
            for (int q = 0; q < 4; ++q) {
                short8 bv = *(const short8*)((const char*)&Bl[0][0] + (64 * w + 16 * q + mr) * 128 + sw);
                acc[q] = __builtin_amdgcn_mfma_f32_16x16x32_bf16(av, bv, acc[q], 0, 0, 0);
            }
        }
        __syncthreads();
    }
    // phase 3: yf32 = acc + ab
    float* yf32 = (float*)&Bl[0][0];   // [16][260]
    #pragma unroll
    for (int q = 0; q < 4; ++q) {
        int col = 64 * w + 16 * q + mr;
        float abv = ab[(size_t)e * DD + col];
        #pragma unroll
        for (int r = 0; r < 4; ++r) {
            int row = 4 * g + r;
            yf32[row * 260 + col] = acc[q][r] + abv;
        }
    }
    __syncthreads();
    // phase 4: row LN(ag,abt)+gelu -> yf32 (f32) + Alf (bf16)
    #pragma unroll
    for (int i = 0; i < 4; ++i) {
        int r = w * 4 + i;
        float4 v = *(const float4*)&yf32[r * 260 + lane * 4];
        float s = v.x + v.y + v.z + v.w;
        float s2 = v.x * v.x + v.y * v.y + v.z * v.z + v.w * v.w;
        #pragma unroll
        for (int o = 1; o < 64; o <<= 1) { s += __shfl_xor(s, o); s2 += __shfl_xor(s2, o); }
        float m = s * (1.f / 256.f);
        float rs = rsqrtf(s2 * (1.f / 256.f) - m * m + 1e-5f);
        float4 gg = *(const float4*)(ag + (size_t)e * DD + lane * 4);
        float4 bb = *(const float4*)(abt + (size_t)e * DD + lane * 4);
        float4 y;
        y.x = gelu_f((v.x - m) * rs * gg.x + bb.x);
        y.y = gelu_f((v.y - m) * rs * gg.y + bb.y);
        y.z = gelu_f((v.z - m) * rs * gg.z + bb.z);
        y.w = gelu_f((v.w - m) * rs * gg.w + bb.w);
        *(float4*)&yf32[r * 260 + lane * 4] = y;
        ushort4 o4 = {f2bf(y.x), f2bf(y.y), f2bf(y.z), f2bf(y.w)};
        *(ushort4*)&Alf[r][lane * 4] = o4;
    }
    __syncthreads();
    // phase 5: gate GEMM [16 x 128]; wave w -> cols 32w..32w+31 (2 frags)
    f32x4 acc2[2];
    acc2[0] = (f32x4){0.f, 0.f, 0.f, 0.f};
    acc2[1] = (f32x4){0.f, 0.f, 0.f, 0.f};
    for (int k0 = 0; k0 < DD; k0 += 64) {
        #pragma unroll
        for (int i = 0; i < 4; ++i) {
            int r = 32 * w + 8 * i + r8;
            gl_lds16(dw1T + (size_t)r * DD + k0 + cg * 8, &Dl[32 * w + 8 * i][0]);
        }
        asm volatile("s_waitcnt vmcnt(0)" ::: "memory");
        __syncthreads();
        #pragma unroll
        for (int kk = 0; kk < 64; kk += 32) {
            int jc = (kk >> 3) + g;
            int sw = ((jc ^ (mr & 7)) << 4);
            short8 av = *(const short8*)&Alf[mr][k0 + kk + g * 8];
            #pragma unroll
            for (int q = 0; q < 2; ++q) {
                short8 bv = *(const short8*)((const char*)&Dl[0][0] + (32 * w + 16 * q + mr) * 128 + sw);
                acc2[q] = __builtin_amdgcn_mfma_f32_16x16x32_bf16(av, bv, acc2[q], 0, 0, 0);
            }
        }
        __syncthreads();
    }
    // phase 6: p[row] = sum_col relu(g+db1)*dw2 ; reduce over mr
    float pv[4] = {0.f, 0.f, 0.f, 0.f};
    #pragma unroll
    for (int q = 0; q < 2; ++q) {
        int col = 32 * w + 16 * q + mr;
        float d1 = db1[col], d2 = dw2[col];
        #pragma unroll
        for (int r = 0; r < 4; ++r)
            pv[r] += fmaxf(acc2[q][r] + d1, 0.f) * d2;
    }
    #pragma unroll
    for (int o = 1; o < 16; o <<= 1) {
        #pragma unroll
        for (int r = 0; r < 4; ++r) pv[r] += __shfl_xor(pv[r], o);
    }
    if (mr == 0) {
        #pragma unroll
        for (int r = 0; r < 4; ++r)
            pg[w][4 * g + r] = pv[r];
    }
    __syncthreads();
    if (tid < TM) {
        float p = pg[0][tid] + pg[1][tid] + pg[2][tid] + pg[3][tid] + db2[0];
        gateS[tid] = 0.8f + 0.4f / (1.f + expf(-p));
    }
    __syncthreads();
    // phase 7: scatter out = y * gate; 256 thr = 16 rows x 16 col-segs
    {
        int row = tid >> 4, c0 = (tid & 15) * 16;
        if (row < nv) {
            int tok = tokS[row];
            float gt = gateS[row];
            #pragma unroll
            for (int j = 0; j < 4; ++j) {
                float4 v = *(const float4*)&yf32[row * 260 + c0 + j * 4];
                v.x *= gt; v.y *= gt; v.z *= gt; v.w *= gt;
                *(float4*)(out + (size_t)tok * DD + c0 + j * 4) = v;
            }
        }
    }
}

extern "C" void kernel_launch(void* const* d_in, const int* in_sizes, int n_in,
                              void* d_out, int out_size, void* d_ws, size_t ws_size,
                              hipStream_t stream) {
    const float* tokens = (const float*)d_in[0];
    const float* ln_g = (const float*)d_in[1];
    const float* ln_b = (const float*)d_in[2];
    const float* pw1 = (const float*)d_in[3];
    const float* pb1 = (const float*)d_in[4];
    const float* pw2 = (const float*)d_in[5];
    const float* pb2 = (const float*)d_in[6];
    const float* emb = (const float*)d_in[7];
    const float* sw1 = (const float*)d_in[8];
    const float* sb1 = (const float*)d_in[9];
    const float* sw2 = (const float*)d_in[10];
    const float* sb2 = (const float*)d_in[11];
    const float* ew1 = (const float*)d_in[12];
    const float* eb1 = (const float*)d_in[13];
    const float* ew2 = (const float*)d_in[14];
    const float* eb2 = (const float*)d_in[15];
    const float* spw1 = (const float*)d_in[16];
    const float* spb1 = (const float*)d_in[17];
    const float* spw2 = (const float*)d_in[18];
    const float* spb2 = (const float*)d_in[19];
    const float* lw1 = (const float*)d_in[20];
    const float* lb1 = (const float*)d_in[21];
    const float* lw2 = (const float*)d_in[22];
    const float* lb2 = (const float*)d_in[23];
    const float* fw = (const float*)d_in[24];
    const float* fb = (const float*)d_in[25];
    const float* fg = (const float*)d_in[26];
    const float* fbeta = (const float*)d_in[27];
    const float* aW = (const float*)d_in[28];
    const float* ab = (const float*)d_in[29];
    const float* ag = (const float*)d_in[30];
    const float* abt = (const float*)d_in[31];
    const float* dw1 = (const float*)d_in[32];
    const float* db1 = (const float*)d_in[33];
    const float* dw2 = (const float*)d_in[34];
    const float* db2 = (const float*)d_in[35];
    const int* levels = (const int*)d_in[36];
    const int* ph = (const int*)d_in[37];
    const int* pw = (const int*)d_in[38];
    float* outp = (float*)d_out;

    char* wsb = (char*)d_ws;
    ushort* x_ln  = (ushort*)wsb;  wsb += (size_t)NTOK * IND * 2;
    ushort* h1    = (ushort*)wsb;  wsb += (size_t)NTOK * DD2 * 2;
    ushort* enh   = (ushort*)wsb;  wsb += (size_t)NTOK * DHH * 2;
    float*  h     = (float*)wsb;   wsb += (size_t)NTOK * DD * 4;
    float*  e_pre = (float*)wsb;   wsb += (size_t)NTOK * DD * 4;
    ushort* pw1T  = (ushort*)wsb;  wsb += (size_t)DD2 * IND * 2;
    ushort* pw2T  = (ushort*)wsb;  wsb += (size_t)DD * DD2 * 2;
    ushort* fwT   = (ushort*)wsb;  wsb += (size_t)DD * DD * 2;
    ushort* aWT   = (ushort*)wsb;  wsb += (size_t)NEXP * DD * DD * 2;
    ushort* dw1T  = (ushort*)wsb;  wsb += (size_t)DHH * DD * 2;
    float*  ctail = (float*)wsb;   wsb += DD * 4;
    int*    sorted = (int*)wsb;    wsb += NTOK * 4;
    int*    tpos   = (int*)wsb;    wsb += NTILE_MAX * 4;
    int*    tcnt   = (int*)wsb;    wsb += NTILE_MAX * 4;
    int*    texp   = (int*)wsb;    wsb += NTILE_MAX * 4;
    int*    meta   = (int*)wsb;    wsb += 64;

    k_pre<<<1 + NWCONV + NTOK / 4, 256, 0, stream>>>(
        pw1, pw2, fw, dw1, aW, pw1T, pw2T, fwT, dw1T, aWT,
        tokens, ln_g, ln_b, sw1, sb1, sw2, sb2, ew1, eb1, ew2, eb2,
        x_ln, enh, levels,
        spw1, spb1, spw2, spb2, lw1, lb1, lw2, lb2, ph, pw, fb,
        sorted, tpos, tcnt, texp, meta, ctail);
    k_gemm1<<<dim3(DD2 / 64, NTOK / 128), 512, 0, stream>>>(x_ln, pw1T, pb1, h1);
    k_mid<<<dim3(DD / 64, 128), 256, 0, stream>>>(
        h1, pw2T, pb2, levels, emb, h, enh, fwT, ctail, e_pre);
    k_adapterF<<<NTILE_MAX, 256, 0, stream>>>(
        h, e_pre, fg, fbeta, aWT, ab, ag, abt, dw1T, db1, dw2, db2,
        sorted, tpos, tcnt, texp, meta, outp);
}

// Round 13
// 64.512 us; speedup vs baseline: 5.5580x; 1.0877x over previous
//
#include <hip/hip_runtime.h>
#include <math.h>

#define NTOK 4096
#define IND 768
#define DD 256
#define DD2 512
#define DHH 128
#define NEXP 51
#define TM 16
#define NTILE_MAX 312
#define NWCONV 968

typedef __attribute__((ext_vector_type(4))) float f32x4;
typedef __attribute__((ext_vector_type(8))) short short8;

__device__ __forceinline__ float gelu_f(float x) {
    return 0.5f * x * (1.0f + erff(x * 0.70710678118654752440f));
}
__device__ __forceinline__ ushort f2bf(float x) {
    unsigned u = __float_as_uint(x);
    return (ushort)((u + 0x7fffu + ((u >> 16) & 1u)) >> 16);
}
// async global->LDS, 16B/lane; LDS dest = wave-uniform base + lane*16
__device__ __forceinline__ void gl_lds16(const ushort* g, ushort* l) {
    __builtin_amdgcn_global_load_lds(
        (const __attribute__((address_space(1))) unsigned int*)g,
        (__attribute__((address_space(3))) unsigned int*)l, 16, 0, 0);
}

// ---- fused pre-pass (round-12 proven) ----
__global__ __launch_bounds__(256) void k_pre(
    const float* __restrict__ pw1, const float* __restrict__ pw2,
    const float* __restrict__ fw, const float* __restrict__ dw1,
    const float* __restrict__ aW,
    ushort* __restrict__ pw1T, ushort* __restrict__ pw2T, ushort* __restrict__ fwT,
    ushort* __restrict__ dw1T, ushort* __restrict__ aWT,
    const float* __restrict__ tokens,
    const float* __restrict__ ln_g, const float* __restrict__ ln_b,
    const float* __restrict__ sw1, const float* __restrict__ sb1,
    const float* __restrict__ sw2, const float* __restrict__ sb2,
    const float* __restrict__ ew1, const float* __restrict__ eb1,
    const float* __restrict__ ew2, const float* __restrict__ eb2,
    ushort* __restrict__ x_ln, ushort* __restrict__ enh,
    const int* __restrict__ levels,
    const float* __restrict__ spw1, const float* __restrict__ spb1,
    const float* __restrict__ spw2, const float* __restrict__ spb2,
    const float* __restrict__ lw1, const float* __restrict__ lb1,
    const float* __restrict__ lw2, const float* __restrict__ lb2,
    const int* __restrict__ ph, const int* __restrict__ pw,
    const float* __restrict__ fb,
    int* __restrict__ sorted, int* __restrict__ tpos, int* __restrict__ tcnt,
    int* __restrict__ texp, int* __restrict__ meta, float* __restrict__ ctail) {
    __shared__ float T[64][65];
    __shared__ int cnt[NEXP], cur[NEXP], offS[NEXP + 1], tileoff[NEXP + 1];
    __shared__ int expS[NTOK];
    __shared__ float hsS[64], hlS[64], cf[128];
    int t = threadIdx.x;

    if (blockIdx.x == 0) {
        if (t < NEXP) cnt[t] = 0;
        if (t < 64) {
            float p0 = (float)ph[0], p1 = (float)pw[0];
            float lvl = (float)levels[0];
            hsS[t] = fmaxf(0.f, p0 * spw1[t] + p1 * spw1[64 + t] + spb1[t]);
            hlS[t] = fmaxf(0.f, lvl * lw1[t] + lb1[t]);
        }
        __syncthreads();
        int myidx[16];
        #pragma unroll
        for (int i = 0; i < 16; ++i) {
            int n = t + i * 256;
            int id = min(max(levels[n * 2], 0), NEXP - 1);
            myidx[i] = id;
            atomicAdd(&cnt[id], 1);
        }
        if (t < 64) {
            float v = spb2[t];
            for (int j = 0; j < 64; ++j) v += hsS[j] * spw2[j * 64 + t];
            cf[t] = v;
        } else if (t < 128) {
            int k = t - 64;
            float v = lb2[k];
            for (int j = 0; j < 64; ++j) v += hlS[j] * lw2[j * 64 + k];
            cf[64 + k] = v;
        }
        __syncthreads();
        if (t == 0) {
            int a = 0, ta = 0;
            for (int e = 0; e < NEXP; ++e) {
                offS[e] = a; cur[e] = a; tileoff[e] = ta;
                ta += (cnt[e] + TM - 1) / TM;
                a += cnt[e];
            }
            offS[NEXP] = a; tileoff[NEXP] = ta;
            meta[0] = ta;
        }
        __syncthreads();
        #pragma unroll
        for (int i = 0; i < 16; ++i) {
            int n = t + i * 256;
            int p = atomicAdd(&cur[myidx[i]], 1);
            sorted[p] = n;
            expS[p] = myidx[i];
        }
        {
            float v = fb[t];
            for (int j = 0; j < 128; ++j) v += cf[j] * fw[(size_t)(128 + j) * DD + t];
            ctail[t] = v;
        }
        __syncthreads();
        #pragma unroll
        for (int i = 0; i < 16; ++i) {
            int p = t + i * 256;
            int e = expS[p];
            int rel = p - offS[e];
            if ((rel & (TM - 1)) == 0) {
                int ti = tileoff[e] + (rel / TM);
                tpos[ti] = p;
                tcnt[ti] = min(TM, offS[e + 1] - p);
                texp[ti] = e;
            }
        }
        return;
    }
    if (blockIdx.x < 1 + NWCONV) {
        int b = blockIdx.x - 1;
        const float* src; ushort* dst; int R, C;
        if (b < 96)       { src = pw1; dst = pw1T; R = IND; C = DD2; }
        else if (b < 128) { b -= 96;  src = pw2; dst = pw2T; R = DD2; C = DD; }
        else if (b < 144) { b -= 128; src = fw;  dst = fwT;  R = DD;  C = DD; }
        else if (b < 152) { b -= 144; src = dw1; dst = dw1T; R = DD;  C = DHH; }
        else { b -= 152; int e = b >> 4; b &= 15;
               src = aW + (size_t)e * DD * DD; dst = aWT + (size_t)e * DD * DD;
               R = DD; C = DD; }
        int tpc = C >> 6;
        int tr = b / tpc, tc = b - tr * tpc;
        int lr = t >> 6, lc = t & 63;
        #pragma unroll
        for (int i = 0; i < 16; ++i) {
            int r = i * 4 + lr;
            T[r][lc] = src[(size_t)(tr * 64 + r) * C + tc * 64 + lc];
        }
        __syncthreads();
        #pragma unroll
        for (int i = 0; i < 16; ++i) {
            int r = i * 4 + lr;
            dst[(size_t)(tc * 64 + r) * R + tr * 64 + lc] = f2bf(T[lc][r]);
        }
        return;
    }
    // per-token stats: one wave per token
    {
        int w = t >> 6, lane = t & 63;
        int n = (blockIdx.x - 1 - NWCONV) * 4 + w;
        const float* x = tokens + (size_t)n * IND;
        float v[12];
        {
            float4 va = *(const float4*)(x + lane * 12);
            float4 vb = *(const float4*)(x + lane * 12 + 4);
            float4 vc = *(const float4*)(x + lane * 12 + 8);
            v[0]=va.x; v[1]=va.y; v[2]=va.z; v[3]=va.w;
            v[4]=vb.x; v[5]=vb.y; v[6]=vb.z; v[7]=vb.w;
            v[8]=vc.x; v[9]=vc.y; v[10]=vc.z; v[11]=vc.w;
        }
        float s = 0.f, s2 = 0.f, es = 0.f;
        #pragma unroll
        for (int j = 0; j < 12; ++j) { s += v[j]; s2 += v[j] * v[j]; }
        float prev = __shfl_up(v[11], 1);
        if (lane > 0) es += fabsf(v[0] - prev);
        #pragma unroll
        for (int j = 1; j < 12; ++j) es += fabsf(v[j] - v[j - 1]);
        #pragma unroll
        for (int o = 1; o < 64; o <<= 1) {
            s  += __shfl_xor(s, o);
            s2 += __shfl_xor(s2, o);
            es += __shfl_xor(es, o);
        }
        float mean = s * (1.f / 768.f);
        float var_u = (s2 - 768.f * mean * mean) * (1.f / 767.f);
        float rstd = rsqrtf(s2 * (1.f / 768.f) - mean * mean + 1e-5f);
        float edge = es * (1.f / 767.f);
        ushort xl[12];
        #pragma unroll
        for (int j = 0; j < 12; ++j) {
            int e = lane * 12 + j;
            xl[j] = f2bf((v[j] - mean) * rstd * ln_g[e] + ln_b[e]);
        }
        ushort* xd = x_ln + (size_t)n * IND + lane * 12;
        *(ushort4*)(xd)     = *(ushort4*)&xl[0];
        *(ushort4*)(xd + 4) = *(ushort4*)&xl[4];
        *(ushort4*)(xd + 8) = *(ushort4*)&xl[8];
        float hs_ = fmaxf(0.f, var_u * sw1[lane] + mean * sw1[64 + lane] + sb1[lane]);
        float he_ = fmaxf(0.f, edge * ew1[lane] + eb1[lane]);
        float acc_s = sb2[lane], acc_e = eb2[lane];
        #pragma unroll 8
        for (int j = 0; j < 64; ++j) {
            float hj = __shfl(hs_, j);
            float ej = __shfl(he_, j);
            acc_s += hj * sw2[j * 64 + lane];
            acc_e += ej * ew2[j * 64 + lane];
        }
        ushort* er = enh + (size_t)n * DHH;
        er[lane] = f2bf(acc_s);
        er[64 + lane] = f2bf(acc_e);
    }
}

// ---- GEMM1: h1 = gelu(x_ln @ pw1T^T + pb1); 128x64 tile, 8 waves (round-12 proven) ----
__global__ __launch_bounds__(512) void k_gemm1(
    const ushort* __restrict__ A, const ushort* __restrict__ BT,
    const float* __restrict__ bias, ushort* __restrict__ Cb) {
    const int N = DD2, K = IND;
    __shared__ ushort Al[128][64];
    __shared__ ushort Bl[64][64];
    int tid = threadIdx.x;
    int w = tid >> 6, lane = tid & 63;
    int g = lane >> 4, mr = lane & 15;
    int mq = w >> 1, nq = w & 1;
    int bm = blockIdx.y * 128, bn = blockIdx.x * 64;
    int r8 = lane >> 3, c = lane & 7, cg = c ^ r8;
    f32x4 acc[2][2];
    #pragma unroll
    for (int im = 0; im < 2; ++im)
        #pragma unroll
        for (int in = 0; in < 2; ++in) acc[im][in] = (f32x4){0.f, 0.f, 0.f, 0.f};
    for (int k0 = 0; k0 < K; k0 += 64) {
        #pragma unroll
        for (int i = 0; i < 2; ++i) {
            int r = 16 * w + 8 * i + r8;
            gl_lds16(A + (size_t)(bm + r) * K + k0 + cg * 8, &Al[16 * w + 8 * i][0]);
        }
        {
            int r = 8 * w + r8;
            gl_lds16(BT + (size_t)(bn + r) * K + k0 + cg * 8, &Bl[8 * w][0]);
        }
        asm volatile("s_waitcnt vmcnt(0)" ::: "memory");
        __syncthreads();
        #pragma unroll
        for (int kk = 0; kk < 64; kk += 32) {
            int jc = (kk >> 3) + g;
            int sw = ((jc ^ (mr & 7)) << 4);
            #pragma unroll
            for (int im = 0; im < 2; ++im) {
                short8 av = *(const short8*)((const char*)&Al[0][0] + (32 * mq + 16 * im + mr) * 128 + sw);
                #pragma unroll
                for (int in = 0; in < 2; ++in) {
                    short8 bv = *(const short8*)((const char*)&Bl[0][0] + (32 * nq + 16 * in + mr) * 128 + sw);
                    acc[im][in] = __builtin_amdgcn_mfma_f32_16x16x32_bf16(av, bv, acc[im][in], 0, 0, 0);
                }
            }
        }
        __syncthreads();
    }
    #pragma unroll
    for (int im = 0; im < 2; ++im) {
        #pragma unroll
        for (int in = 0; in < 2; ++in) {
            int col = bn + 32 * nq + 16 * in + mr;
            float bv = bias[col];
            #pragma unroll
            for (int r = 0; r < 4; ++r) {
                int row = bm + 32 * mq + 16 * im + 4 * g + r;
                Cb[(size_t)row * N + col] = f2bf(gelu_f(acc[im][in][r] + bv));
            }
        }
    }
}

// ---- mega-adapter: per 16-token tile: h=h1@pw2+emb, e=enh@fw+ctail, hfull,
//      expert GEMM, LN+gelu, gate GEMM, scale, scatter.  256 thr / 4 waves ----
__global__ __launch_bounds__(256) void k_adapterF(
    const ushort* __restrict__ h1, const ushort* __restrict__ enh,
    const ushort* __restrict__ pw2T, const float* __restrict__ pb2,
    const float* __restrict__ emb,
    const ushort* __restrict__ fwT, const float* __restrict__ ctail,
    const float* __restrict__ fg, const float* __restrict__ fbeta,
    const ushort* __restrict__ aWT, const float* __restrict__ ab,
    const float* __restrict__ ag, const float* __restrict__ abt,
    const ushort* __restrict__ dw1T, const float* __restrict__ db1,
    const float* __restrict__ dw2, const float* __restrict__ db2,
    const int* __restrict__ sorted, const int* __restrict__ tpos,
    const int* __restrict__ tcnt, const int* __restrict__ texp,
    const int* __restrict__ meta, float* __restrict__ out) {
    __shared__ __align__(16) char smA[16384];     // H1[16][512] bf16 ; later Dl[128][64]
    __shared__ __align__(16) char smB[32768];     // Bl[256][64] bf16 ; later yf32[16][260]
    __shared__ __align__(16) ushort Alf[TM][264]; // hfull bf16, later y bf16
    __shared__ __align__(16) ushort EnhS[TM][128];
    __shared__ int tokS[TM];
    __shared__ float redS[4][TM][2];
    __shared__ float gateS[TM];
    __shared__ float pg[4][TM];
    ushort* H1p = (ushort*)smA;
    ushort* Dlp = (ushort*)smA;
    ushort* Blp = (ushort*)smB;
    float* yf32 = (float*)smB;

    int b = blockIdx.x;
    if (b >= meta[0]) return;
    int tid = threadIdx.x, w = tid >> 6, lane = tid & 63;
    int g = lane >> 4, mr = lane & 15;
    int r8 = lane >> 3, c = lane & 7, cg = c ^ r8;
    int e = texp[b], base = tpos[b], nv = tcnt[b];
    if (tid < TM) tokS[tid] = sorted[base + min(tid, nv - 1)];
    __syncthreads();

    // stage H1 tile [16][512] (swizzled) + EnhS [16][128] (swizzled)
    #pragma unroll
    for (int i = 0; i < 4; ++i) {
        int r = 4 * w + i;
        int tok = tokS[r];
        gl_lds16(h1 + (size_t)tok * DD2 + ((lane ^ (r & 7)) << 3), H1p + r * DD2);
    }
    {
        int row = 4 * w + (lane >> 4);
        int tok = tokS[row];
        int ch = lane & 15;
        gl_lds16(enh + (size_t)tok * DHH + ((ch ^ (row & 7)) << 3), &EnhS[4 * w][0]);
    }
    asm volatile("s_waitcnt vmcnt(0)" ::: "memory");
    __syncthreads();

    // phase A: hacc[16x256] = H1 @ pw2T^T  (K=512)
    f32x4 hacc[4];
    #pragma unroll
    for (int q = 0; q < 4; ++q) hacc[q] = (f32x4){0.f, 0.f, 0.f, 0.f};
    for (int k0 = 0; k0 < DD2; k0 += 64) {
        #pragma unroll
        for (int i = 0; i < 8; ++i) {
            int r = 64 * w + 8 * i + r8;
            gl_lds16(pw2T + (size_t)r * DD2 + k0 + cg * 8, Blp + (64 * w + 8 * i) * 64);
        }
        asm volatile("s_waitcnt vmcnt(0)" ::: "memory");
        __syncthreads();
        #pragma unroll
        for (int kk = 0; kk < 64; kk += 32) {
            int jc = ((k0 + kk) >> 3) + g;
            short8 av = *(const short8*)((const char*)H1p + mr * 1024 + ((jc ^ (mr & 7)) << 4));
            int swb = (((kk >> 3) + g) ^ (mr & 7)) << 4;
            #pragma unroll
            for (int q = 0; q < 4; ++q) {
                short8 bv = *(const short8*)((const char*)Blp + (64 * w + 16 * q + mr) * 128 + swb);
                hacc[q] = __builtin_amdgcn_mfma_f32_16x16x32_bf16(av, bv, hacc[q], 0, 0, 0);
            }
        }
        __syncthreads();
    }
    // phase B: eacc[16x256] = EnhS @ fwT^T  (K=128)
    f32x4 eacc[4];
    #pragma unroll
    for (int q = 0; q < 4; ++q) eacc[q] = (f32x4){0.f, 0.f, 0.f, 0.f};
    for (int k0 = 0; k0 < DHH; k0 += 64) {
        #pragma unroll
        for (int i = 0; i < 8; ++i) {
            int r = 64 * w + 8 * i + r8;
            gl_lds16(fwT + (size_t)r * DD + k0 + cg * 8, Blp + (64 * w + 8 * i) * 64);
        }
        asm volatile("s_waitcnt vmcnt(0)" ::: "memory");
        __syncthreads();
        #pragma unroll
        for (int kk = 0; kk < 64; kk += 32) {
            int jc = ((k0 + kk) >> 3) + g;
            short8 av = *(const short8*)((const char*)&EnhS[0][0] + mr * 256 + ((jc ^ (mr & 7)) << 4));
            int swb = (((kk >> 3) + g) ^ (mr & 7)) << 4;
            #pragma unroll
            for (int q = 0; q < 4; ++q) {
                short8 bv = *(const short8*)((const char*)Blp + (64 * w + 16 * q + mr) * 128 + swb);
                eacc[q] = __builtin_amdgcn_mfma_f32_16x16x32_bf16(av, bv, eacc[q], 0, 0, 0);
            }
        }
        __syncthreads();
    }
    // phase C: h = hacc + pb2 + emb[e]; e_pre = eacc + ctail; LN(e_pre) rows; hfull -> Alf
    #pragma unroll
    for (int q = 0; q < 4; ++q) {
        int col = 64 * w + 16 * q + mr;
        float hb = pb2[col] + emb[(size_t)e * DD + col];
        float cb2 = ctail[col];
        #pragma unroll
        for (int r4 = 0; r4 < 4; ++r4) {
            hacc[q][r4] += hb;
            eacc[q][r4] += cb2;
        }
    }
    {
        float s[4], s2[4];
        #pragma unroll
        for (int r4 = 0; r4 < 4; ++r4) {
            s[r4] = eacc[0][r4] + eacc[1][r4] + eacc[2][r4] + eacc[3][r4];
            s2[r4] = eacc[0][r4]*eacc[0][r4] + eacc[1][r4]*eacc[1][r4]
                   + eacc[2][r4]*eacc[2][r4] + eacc[3][r4]*eacc[3][r4];
        }
        #pragma unroll
        for (int o = 1; o < 16; o <<= 1) {
            #pragma unroll
            for (int r4 = 0; r4 < 4; ++r4) {
                s[r4]  += __shfl_xor(s[r4], o);
                s2[r4] += __shfl_xor(s2[r4], o);
            }
        }
        if (mr == 0) {
            #pragma unroll
            for (int r4 = 0; r4 < 4; ++r4) {
                redS[w][4 * g + r4][0] = s[r4];
                redS[w][4 * g + r4][1] = s2[r4];
            }
        }
    }
    __syncthreads();
    #pragma unroll
    for (int r4 = 0; r4 < 4; ++r4) {
        int row = 4 * g + r4;
        float S  = redS[0][row][0] + redS[1][row][0] + redS[2][row][0] + redS[3][row][0];
        float S2 = redS[0][row][1] + redS[1][row][1] + redS[2][row][1] + redS[3][row][1];
        float m = S * (1.f / 256.f);
        float rs = rsqrtf(S2 * (1.f / 256.f) - m * m + 1e-5f);
        #pragma unroll
        for (int q = 0; q < 4; ++q) {
            int col = 64 * w + 16 * q + mr;
            float enhv = gelu_f((eacc[q][r4] - m) * rs * fg[col] + fbeta[col]);
            Alf[row][col] = f2bf(hacc[q][r4] + 0.3f * enhv);
        }
    }
    __syncthreads();
    // phase D: expert GEMM yacc[16x256] = Alf @ aWT[e]^T
    const ushort* We = aWT + (size_t)e * DD * DD;
    f32x4 yacc[4];
    #pragma unroll
    for (int q = 0; q < 4; ++q) yacc[q] = (f32x4){0.f, 0.f, 0.f, 0.f};
    for (int k0 = 0; k0 < DD; k0 += 64) {
        #pragma unroll
        for (int i = 0; i < 8; ++i) {
            int r = 64 * w + 8 * i + r8;
            gl_lds16(We + (size_t)r * DD + k0 + cg * 8, Blp + (64 * w + 8 * i) * 64);
        }
        asm volatile("s_waitcnt vmcnt(0)" ::: "memory");
        __syncthreads();
        #pragma unroll
        for (int kk = 0; kk < 64; kk += 32) {
            short8 av = *(const short8*)&Alf[mr][k0 + kk + g * 8];
            int swb = (((kk >> 3) + g) ^ (mr & 7)) << 4;
            #pragma unroll
            for (int q = 0; q < 4; ++q) {
                short8 bv = *(const short8*)((const char*)Blp + (64 * w + 16 * q + mr) * 128 + swb);
                yacc[q] = __builtin_amdgcn_mfma_f32_16x16x32_bf16(av, bv, yacc[q], 0, 0, 0);
            }
        }
        __syncthreads();
    }
    // y_pre = yacc + ab -> yf32 (Bl region)
    #pragma unroll
    for (int q = 0; q < 4; ++q) {
        int col = 64 * w + 16 * q + mr;
        float abv = ab[(size_t)e * DD + col];
        #pragma unroll
        for (int r4 = 0; r4 < 4; ++r4) {
            yf32[(4 * g + r4) * 260 + col] = yacc[q][r4] + abv;
        }
    }
    __syncthreads();
    // phase E: per-row LN(ag,abt)+gelu -> yf32 (f32) + Alf (bf16)
    #pragma unroll
    for (int i = 0; i < 4; ++i) {
        int r = w * 4 + i;
        float4 v = *(const float4*)&yf32[r * 260 + lane * 4];
        float s = v.x + v.y + v.z + v.w;
        float s2 = v.x * v.x + v.y * v.y + v.z * v.z + v.w * v.w;
        #pragma unroll
        for (int o = 1; o < 64; o <<= 1) { s += __shfl_xor(s, o); s2 += __shfl_xor(s2, o); }
        float m = s * (1.f / 256.f);
        float rs = rsqrtf(s2 * (1.f / 256.f) - m * m + 1e-5f);
        float4 gg = *(const float4*)(ag + (size_t)e * DD + lane * 4);
        float4 bb = *(const float4*)(abt + (size_t)e * DD + lane * 4);
        float4 y;
        y.x = gelu_f((v.x - m) * rs * gg.x + bb.x);
        y.y = gelu_f((v.y - m) * rs * gg.y + bb.y);
        y.z = gelu_f((v.z - m) * rs * gg.z + bb.z);
        y.w = gelu_f((v.w - m) * rs * gg.w + bb.w);
        *(float4*)&yf32[r * 260 + lane * 4] = y;
        ushort4 o4 = {f2bf(y.x), f2bf(y.y), f2bf(y.z), f2bf(y.w)};
        *(ushort4*)&Alf[r][lane * 4] = o4;
    }
    __syncthreads();
    // phase F: gate GEMM [16x128] = y_bf @ dw1T^T (dw1 staged into smA/Dl)
    f32x4 acc2[2];
    acc2[0] = (f32x4){0.f, 0.f, 0.f, 0.f};
    acc2[1] = (f32x4){0.f, 0.f, 0.f, 0.f};
    for (int k0 = 0; k0 < DD; k0 += 64) {
        #pragma unroll
        for (int i = 0; i < 4; ++i) {
            int r = 32 * w + 8 * i + r8;
            gl_lds16(dw1T + (size_t)r * DD + k0 + cg * 8, Dlp + (32 * w + 8 * i) * 64);
        }
        asm volatile("s_waitcnt vmcnt(0)" ::: "memory");
        __syncthreads();
        #pragma unroll
        for (int kk = 0; kk < 64; kk += 32) {
            short8 av = *(const short8*)&Alf[mr][k0 + kk + g * 8];
            int swb = (((kk >> 3) + g) ^ (mr & 7)) << 4;
            #pragma unroll
            for (int q = 0; q < 2; ++q) {
                short8 bv = *(const short8*)((const char*)Dlp + (32 * w + 16 * q + mr) * 128 + swb);
                acc2[q] = __builtin_amdgcn_mfma_f32_16x16x32_bf16(av, bv, acc2[q], 0, 0, 0);
            }
        }
        __syncthreads();
    }
    // phase G: gate reduce + sigmoid + scatter
    float pv[4] = {0.f, 0.f, 0.f, 0.f};
    #pragma unroll
    for (int q = 0; q < 2; ++q) {
        int col = 32 * w + 16 * q + mr;
        float d1 = db1[col], d2 = dw2[col];
        #pragma unroll
        for (int r4 = 0; r4 < 4; ++r4)
            pv[r4] += fmaxf(acc2[q][r4] + d1, 0.f) * d2;
    }
    #pragma unroll
    for (int o = 1; o < 16; o <<= 1) {
        #pragma unroll
        for (int r4 = 0; r4 < 4; ++r4) pv[r4] += __shfl_xor(pv[r4], o);
    }
    if (mr == 0) {
        #pragma unroll
        for (int r4 = 0; r4 < 4; ++r4)
            pg[w][4 * g + r4] = pv[r4];
    }
    __syncthreads();
    if (tid < TM) {
        float p = pg[0][tid] + pg[1][tid] + pg[2][tid] + pg[3][tid] + db2[0];
        gateS[tid] = 0.8f + 0.4f / (1.f + expf(-p));
    }
    __syncthreads();
    {
        int row = tid >> 4, c0 = (tid & 15) * 16;
        if (row < nv) {
            int tok = tokS[row];
            float gt = gateS[row];
            #pragma unroll
            for (int j = 0; j < 4; ++j) {
                float4 v = *(const float4*)&yf32[row * 260 + c0 + j * 4];
                v.x *= gt; v.y *= gt; v.z *= gt; v.w *= gt;
                *(float4*)(out + (size_t)tok * DD + c0 + j * 4) = v;
            }
        }
    }
}

extern "C" void kernel_launch(void* const* d_in, const int* in_sizes, int n_in,
                              void* d_out, int out_size, void* d_ws, size_t ws_size,
                              hipStream_t stream) {
    const float* tokens = (const float*)d_in[0];
    const float* ln_g = (const float*)d_in[1];
    const float* ln_b = (const float*)d_in[2];
    const float* pw1 = (const float*)d_in[3];
    const float* pb1 = (const float*)d_in[4];
    const float* pw2 = (const float*)d_in[5];
    const float* pb2 = (const float*)d_in[6];
    const float* emb = (const float*)d_in[7];
    const float* sw1 = (const float*)d_in[8];
    const float* sb1 = (const float*)d_in[9];
    const float* sw2 = (const float*)d_in[10];
    const float* sb2 = (const float*)d_in[11];
    const float* ew1 = (const float*)d_in[12];
    const float* eb1 = (const float*)d_in[13];
    const float* ew2 = (const float*)d_in[14];
    const float* eb2 = (const float*)d_in[15];
    const float* spw1 = (const float*)d_in[16];
    const float* spb1 = (const float*)d_in[17];
    const float* spw2 = (const float*)d_in[18];
    const float* spb2 = (const float*)d_in[19];
    const float* lw1 = (const float*)d_in[20];
    const float* lb1 = (const float*)d_in[21];
    const float* lw2 = (const float*)d_in[22];
    const float* lb2 = (const float*)d_in[23];
    const float* fw = (const float*)d_in[24];
    const float* fb = (const float*)d_in[25];
    const float* fg = (const float*)d_in[26];
    const float* fbeta = (const float*)d_in[27];
    const float* aW = (const float*)d_in[28];
    const float* ab = (const float*)d_in[29];
    const float* ag = (const float*)d_in[30];
    const float* abt = (const float*)d_in[31];
    const float* dw1 = (const float*)d_in[32];
    const float* db1 = (const float*)d_in[33];
    const float* dw2 = (const float*)d_in[34];
    const float* db2 = (const float*)d_in[35];
    const int* levels = (const int*)d_in[36];
    const int* ph = (const int*)d_in[37];
    const int* pw = (const int*)d_in[38];
    float* outp = (float*)d_out;

    char* wsb = (char*)d_ws;
    ushort* x_ln  = (ushort*)wsb;  wsb += (size_t)NTOK * IND * 2;
    ushort* h1    = (ushort*)wsb;  wsb += (size_t)NTOK * DD2 * 2;
    ushort* enh   = (ushort*)wsb;  wsb += (size_t)NTOK * DHH * 2;
    ushort* pw1T  = (ushort*)wsb;  wsb += (size_t)DD2 * IND * 2;
    ushort* pw2T  = (ushort*)wsb;  wsb += (size_t)DD * DD2 * 2;
    ushort* fwT   = (ushort*)wsb;  wsb += (size_t)DD * DD * 2;
    ushort* aWT   = (ushort*)wsb;  wsb += (size_t)NEXP * DD * DD * 2;
    ushort* dw1T  = (ushort*)wsb;  wsb += (size_t)DHH * DD * 2;
    float*  ctail = (float*)wsb;   wsb += DD * 4;
    int*    sorted = (int*)wsb;    wsb += NTOK * 4;
    int*    tpos   = (int*)wsb;    wsb += NTILE_MAX * 4;
    int*    tcnt   = (int*)wsb;    wsb += NTILE_MAX * 4;
    int*    texp   = (int*)wsb;    wsb += NTILE_MAX * 4;
    int*    meta   = (int*)wsb;    wsb += 64;

    k_pre<<<1 + NWCONV + NTOK / 4, 256, 0, stream>>>(
        pw1, pw2, fw, dw1, aW, pw1T, pw2T, fwT, dw1T, aWT,
        tokens, ln_g, ln_b, sw1, sb1, sw2, sb2, ew1, eb1, ew2, eb2,
        x_ln, enh, levels,
        spw1, spb1, spw2, spb2, lw1, lb1, lw2, lb2, ph, pw, fb,
        sorted, tpos, tcnt, texp, meta, ctail);
    k_gemm1<<<dim3(DD2 / 64, NTOK / 128), 512, 0, stream>>>(x_ln, pw1T, pb1, h1);
    k_adapterF<<<NTILE_MAX, 256, 0, stream>>>(
        h1, enh, pw2T, pb2, emb, fwT, ctail, fg, fbeta,
        aWT, ab, ag, abt, dw1T, db1, dw2, db2,
        sorted, tpos, tcnt, texp, meta, outp);
}